// Round 1
// baseline (614.133 us; speedup 1.0000x reference)
//
#include <hip/hip_runtime.h>
#include <hip/hip_bf16.h>

#define NV 1024
#define NE 2048
#define NH 4

typedef unsigned short u16;

__device__ __forceinline__ float bf2f(u16 u) { return __uint_as_float(((unsigned)u) << 16); }
__device__ __forceinline__ u16 f2bf(float f) {
  unsigned x = __float_as_uint(f);
  return (u16)((x + 0x7fffu + ((x >> 16) & 1u)) >> 16);
}

// Generic tiled f32 matmul: C(M,N) = A(M,K) @ B(K,N), 64x64 tile, BK=16,
// 256 threads, 4x4 microtile. TAISBF: A is bf16. TBINT: B is int (>0 -> 1.0f).
// EPI 0: plain f32 store. EPI 1: bf16 store of acc * G[m,n]. EPI 2: attention
// output epilogue (adds Wh and self-correction).
template <int TAISBF, int TBINT, int EPI>
__global__ __launch_bounds__(256) void mm_kernel(
    const void* __restrict__ Ap, int lda, long sA,
    const void* __restrict__ Bp, int ldb, long sB,
    void* __restrict__ Cp, int ldc, long sC, int K,
    const float* __restrict__ Gm, const float* __restrict__ WhP,
    const float* __restrict__ svP) {
  __shared__ float As[16][68];
  __shared__ float Bs[16][68];
  const int t = threadIdx.x;
  const int tx = t & 15, ty = t >> 4;
  const int m0 = blockIdx.y * 64, n0 = blockIdx.x * 64, z = blockIdx.z;
  const int lr = t >> 2, lc4 = (t & 3) * 4;
  const int bk = t >> 4, bn = (t & 15) * 4;
  float acc[4][4] = {};
  for (int k0 = 0; k0 < K; k0 += 16) {
    if constexpr (TAISBF) {
      const u16* Az = (const u16*)Ap + sA * z;
      ushort4 a4 = *(const ushort4*)(Az + (long)(m0 + lr) * lda + k0 + lc4);
      As[lc4 + 0][lr] = bf2f(a4.x);
      As[lc4 + 1][lr] = bf2f(a4.y);
      As[lc4 + 2][lr] = bf2f(a4.z);
      As[lc4 + 3][lr] = bf2f(a4.w);
    } else {
      const float* Az = (const float*)Ap + sA * z;
      float4 a4 = *(const float4*)(Az + (long)(m0 + lr) * lda + k0 + lc4);
      As[lc4 + 0][lr] = a4.x;
      As[lc4 + 1][lr] = a4.y;
      As[lc4 + 2][lr] = a4.z;
      As[lc4 + 3][lr] = a4.w;
    }
    if constexpr (TBINT) {
      const int* Bz = (const int*)Bp + sB * z;
      int4 b4 = *(const int4*)(Bz + (long)(k0 + bk) * ldb + n0 + bn);
      Bs[bk][bn + 0] = b4.x > 0 ? 1.f : 0.f;
      Bs[bk][bn + 1] = b4.y > 0 ? 1.f : 0.f;
      Bs[bk][bn + 2] = b4.z > 0 ? 1.f : 0.f;
      Bs[bk][bn + 3] = b4.w > 0 ? 1.f : 0.f;
    } else {
      const float* Bz = (const float*)Bp + sB * z;
      float4 b4 = *(const float4*)(Bz + (long)(k0 + bk) * ldb + n0 + bn);
      Bs[bk][bn + 0] = b4.x;
      Bs[bk][bn + 1] = b4.y;
      Bs[bk][bn + 2] = b4.z;
      Bs[bk][bn + 3] = b4.w;
    }
    __syncthreads();
#pragma unroll
    for (int kk = 0; kk < 16; kk++) {
      float a[4], b[4];
      *(float4*)a = *(const float4*)&As[kk][ty * 4];
      *(float4*)b = *(const float4*)&Bs[kk][tx * 4];
#pragma unroll
      for (int i = 0; i < 4; i++)
#pragma unroll
        for (int j = 0; j < 4; j++) acc[i][j] = fmaf(a[i], b[j], acc[i][j]);
    }
    __syncthreads();
  }
#pragma unroll
  for (int i = 0; i < 4; i++) {
    const int m = m0 + ty * 4 + i;
#pragma unroll
    for (int j = 0; j < 4; j++) {
      const int n = n0 + tx * 4 + j;
      float vv = acc[i][j];
      if constexpr (EPI == 0) {
        ((float*)Cp)[sC * z + (long)m * ldc + n] = vv;
      } else if constexpr (EPI == 1) {
        ((u16*)Cp)[sC * z + (long)m * ldc + n] = f2bf(vv * Gm[(long)m * NV + n]);
      } else {
        float w = WhP[(long)m * 256 + z * 64 + n];
        ((float*)Cp)[(long)m * 256 + z * 64 + n] =
            vv + w * (1.f - svP[m * 4 + z] * Gm[(long)m * NV + m]);
      }
    }
  }
}

// cnt_e[e] = #vertices in edge e
__global__ __launch_bounds__(256) void k_cnt(const int* __restrict__ inc, float* __restrict__ cnt) {
  int e = blockIdx.x * 256 + threadIdx.x;
  int s = 0;
  for (int v = 0; v < NV; v++) s += (inc[(long)v * NE + e] > 0);
  cnt[e] = (float)s;
}

// Mt[e*V+v] = M[v,e]
__global__ __launch_bounds__(256) void k_build(const int* __restrict__ inc, float* __restrict__ Mt) {
  long idx = (long)blockIdx.x * 256 + threadIdx.x;
  int v = (int)(idx >> 11), e = (int)(idx & 2047);
  Mt[(long)e * NV + v] = inc[idx] > 0 ? 1.f : 0.f;
}

// qv[v,h] = Whh[v,h,:].a_v ; qe[v,h] = Whh[v,h,:].a_e
__global__ __launch_bounds__(256) void k_qse1(const float* __restrict__ Wh,
                                              const float* __restrict__ attn_w,
                                              float* __restrict__ qv, float* __restrict__ qe) {
  int v = blockIdx.x, t = threadIdx.x;
  int d = t & 63, h = t >> 6;
  float x = Wh[(long)v * 256 + t];
  float pv = x * attn_w[d];
  float pe = x * attn_w[64 + d];
  for (int s = 32; s; s >>= 1) {
    pv += __shfl_down(pv, s);
    pe += __shfl_down(pe, s);
  }
  if (d == 0) {
    qv[v * 4 + h] = pv;
    qe[v * 4 + h] = pe;
  }
}

// se[e,h] = (sum_v M[v,e]*qe[v,h]) / max(cnt_e,1)
__global__ __launch_bounds__(256) void k_se(const int* __restrict__ inc,
                                            const float* __restrict__ qe,
                                            const float* __restrict__ cnt,
                                            float* __restrict__ se) {
  int e = blockIdx.x * 256 + threadIdx.x;
  float s0 = 0, s1 = 0, s2 = 0, s3 = 0;
  for (int v = 0; v < NV; v++) {
    if (inc[(long)v * NE + e] > 0) {
      s0 += qe[v * 4 + 0];
      s1 += qe[v * 4 + 1];
      s2 += qe[v * 4 + 2];
      s3 += qe[v * 4 + 3];
    }
  }
  float dg = fmaxf(cnt[e], 1.f);
  se[e * 4 + 0] = s0 / dg;
  se[e * 4 + 1] = s1 / dg;
  se[e * 4 + 2] = s2 / dg;
  se[e * 4 + 3] = s3 / dg;
}

// Per (v,u): gate G via 2->32->1 MLP, and wce = ce . (enc_w @ a_c)
__global__ __launch_bounds__(256) void k_G(const float* __restrict__ ce,
                                           const float* __restrict__ enc_w,
                                           const float* __restrict__ attn_w,
                                           const float* __restrict__ g1w,
                                           const float* __restrict__ g1b,
                                           const float* __restrict__ g2w,
                                           const float* __restrict__ g2b,
                                           float* __restrict__ G, float* __restrict__ wce) {
  long idx = (long)blockIdx.x * 256 + threadIdx.x;
  float2 c = *(const float2*)(ce + idx * 2);
  float ew0 = 0, ew1 = 0;
#pragma unroll
  for (int j = 0; j < 8; j++) {
    float ac = attn_w[128 + j];
    ew0 += enc_w[j] * ac;
    ew1 += enc_w[8 + j] * ac;
  }
  wce[idx] = c.x * ew0 + c.y * ew1;
  float s = g2b[0];
#pragma unroll
  for (int j = 0; j < 32; j++) {
    float zz = fmaxf(c.x * g1w[j] + c.y * g1w[32 + j] + g1b[j], 0.f);
    s = fmaf(zz, g2w[j], s);
  }
  G[idx] = 1.f / (1.f + expf(-s));
}

// Per v: scores -> leaky_relu -> mask -> softmax over E -> ap (bf16 planes), s_v
__global__ __launch_bounds__(256) void k_softmax(
    const float* __restrict__ P, const int* __restrict__ inc, const float* __restrict__ cnt,
    const float* __restrict__ qv, const float* __restrict__ se, const float* __restrict__ ce,
    const float* __restrict__ enc_w, const float* __restrict__ attn_w,
    const float* __restrict__ enc_b, u16* __restrict__ ap, float* __restrict__ sv) {
  int v = blockIdx.x, t = threadIdx.x;
  float ew0 = 0, ew1 = 0, ebac = 0;
#pragma unroll
  for (int j = 0; j < 8; j++) {
    float ac = attn_w[128 + j];
    ew0 += enc_w[j] * ac;
    ew1 += enc_w[8 + j] * ac;
    ebac += enc_b[j] * ac;
  }
  float dce = ce[((long)v * NV + v) * 2] * ew0 + ce[((long)v * NV + v) * 2 + 1] * ew1;
  float svh[4];
#pragma unroll
  for (int hh = 0; hh < 4; hh++) svh[hh] = qv[v * 4 + hh];

  float sc[8][4];
  float invn[8], msk[8];
  float mx[4] = {-3e38f, -3e38f, -3e38f, -3e38f};
  for (int i = 0; i < 8; i++) {
    int e = t + i * 256;
    float mask = inc[(long)v * NE + e] > 0 ? 1.f : 0.f;
    float nve = cnt[e] - mask;
    float inv = nve > 0.f ? 1.f / nve : 0.f;
    invn[i] = inv;
    msk[i] = mask;
    float cc = inv * (P[(long)v * NE + e] - mask * dce) + ebac;
#pragma unroll
    for (int hh = 0; hh < 4; hh++) {
      float s = svh[hh] + se[e * 4 + hh] + cc;
      s = s > 0.f ? s : 0.2f * s;
      s = mask > 0.f ? s : -1e9f;
      sc[i][hh] = s;
      mx[hh] = fmaxf(mx[hh], s);
    }
  }
  __shared__ float red[4][256];
#pragma unroll
  for (int hh = 0; hh < 4; hh++) red[hh][t] = mx[hh];
  __syncthreads();
  for (int s = 128; s; s >>= 1) {
    if (t < s)
#pragma unroll
      for (int hh = 0; hh < 4; hh++) red[hh][t] = fmaxf(red[hh][t], red[hh][t + s]);
    __syncthreads();
  }
  float gm[4];
#pragma unroll
  for (int hh = 0; hh < 4; hh++) gm[hh] = red[hh][0];
  __syncthreads();

  float lsum[4] = {0, 0, 0, 0};
  for (int i = 0; i < 8; i++)
#pragma unroll
    for (int hh = 0; hh < 4; hh++) {
      float p = expf(sc[i][hh] - gm[hh]);
      sc[i][hh] = p;
      lsum[hh] += p;
    }
#pragma unroll
  for (int hh = 0; hh < 4; hh++) red[hh][t] = lsum[hh];
  __syncthreads();
  for (int s = 128; s; s >>= 1) {
    if (t < s)
#pragma unroll
      for (int hh = 0; hh < 4; hh++) red[hh][t] += red[hh][t + s];
    __syncthreads();
  }
  float inv_s[4];
#pragma unroll
  for (int hh = 0; hh < 4; hh++) inv_s[hh] = 1.f / red[hh][0];
  __syncthreads();

  float lsv[4] = {0, 0, 0, 0};
  for (int i = 0; i < 8; i++) {
    int e = t + i * 256;
#pragma unroll
    for (int hh = 0; hh < 4; hh++) {
      float a = sc[i][hh] * inv_s[hh] * msk[i] * invn[i];
      ap[(long)hh * NV * NE + (long)v * NE + e] = f2bf(a);
      lsv[hh] += a;
    }
  }
#pragma unroll
  for (int hh = 0; hh < 4; hh++) red[hh][t] = lsv[hh];
  __syncthreads();
  for (int s = 128; s; s >>= 1) {
    if (t < s)
#pragma unroll
      for (int hh = 0; hh < 4; hh++) red[hh][t] += red[hh][t + s];
    __syncthreads();
  }
  if (t == 0)
#pragma unroll
    for (int hh = 0; hh < 4; hh++) sv[v * 4 + hh] = red[hh][0];
}

// LayerNorm over 256, in place, two-pass
__global__ __launch_bounds__(256) void k_ln(float* __restrict__ out, const float* __restrict__ lng,
                                            const float* __restrict__ lnb) {
  int v = blockIdx.x, t = threadIdx.x;
  __shared__ float red[256];
  float x = out[(long)v * 256 + t];
  red[t] = x;
  __syncthreads();
  for (int s = 128; s; s >>= 1) {
    if (t < s) red[t] += red[t + s];
    __syncthreads();
  }
  float mu = red[0] * (1.f / 256.f);
  __syncthreads();
  float d = x - mu;
  red[t] = d * d;
  __syncthreads();
  for (int s = 128; s; s >>= 1) {
    if (t < s) red[t] += red[t + s];
    __syncthreads();
  }
  float var = red[0] * (1.f / 256.f);
  out[(long)v * 256 + t] = d / sqrtf(var + 1e-5f) * lng[t] + lnb[t];
}

extern "C" void kernel_launch(void* const* d_in, const int* in_sizes, int n_in,
                              void* d_out, int out_size, void* d_ws, size_t ws_size,
                              hipStream_t stream) {
  const float* h = (const float*)d_in[0];
  const float* ce = (const float*)d_in[1];
  const float* W = (const float*)d_in[2];
  const float* attn_w = (const float*)d_in[3];
  const float* enc_w = (const float*)d_in[4];
  const float* enc_b = (const float*)d_in[5];
  const float* g1w = (const float*)d_in[6];
  const float* g1b = (const float*)d_in[7];
  const float* g2w = (const float*)d_in[8];
  const float* g2b = (const float*)d_in[9];
  const float* lng = (const float*)d_in[10];
  const float* lnb = (const float*)d_in[11];
  const int* inc = (const int*)d_in[12];
  float* out = (float*)d_out;

  size_t off = 0;
  char* base = (char*)d_ws;
  auto alloc = [&](size_t bytes) {
    void* p = base + off;
    off += (bytes + 255) & ~(size_t)255;
    return p;
  };
  float* Wh = (float*)alloc((size_t)NV * 256 * 4);
  float* cnt = (float*)alloc((size_t)NE * 4);
  float* qv = (float*)alloc((size_t)NV * 4 * 4);
  float* qe = (float*)alloc((size_t)NV * 4 * 4);
  float* se = (float*)alloc((size_t)NE * 4 * 4);
  float* sv = (float*)alloc((size_t)NV * 4 * 4);
  float* G = (float*)alloc((size_t)NV * NV * 4);
  float* wce = (float*)alloc((size_t)NV * NV * 4);
  float* Mt = (float*)alloc((size_t)NE * NV * 4);
  float* P = (float*)alloc((size_t)NV * NE * 4);
  u16* ap = (u16*)alloc((size_t)4 * NV * NE * 2);
  u16* Bh = (u16*)alloc((size_t)4 * NV * NV * 2);
  (void)ws_size;
  (void)in_sizes;
  (void)n_in;
  (void)out_size;

  // 1. Wh = h @ W  (1024x256x256)
  mm_kernel<0, 0, 0><<<dim3(256 / 64, NV / 64, 1), 256, 0, stream>>>(
      h, 256, 0, W, 256, 0, Wh, 256, 0, 256, nullptr, nullptr, nullptr);
  // 2. cnt_e
  k_cnt<<<NE / 256, 256, 0, stream>>>(inc, cnt);
  // 3. Mt (transpose of M)
  k_build<<<(NV * NE) / 256, 256, 0, stream>>>(inc, Mt);
  // 4. qv, qe
  k_qse1<<<NV, 256, 0, stream>>>(Wh, attn_w, qv, qe);
  // 5. se
  k_se<<<NE / 256, 256, 0, stream>>>(inc, qe, cnt, se);
  // 6. G, wce
  k_G<<<(NV * NV) / 256, 256, 0, stream>>>(ce, enc_w, attn_w, g1w, g1b, g2w, g2b, G, wce);
  // 7. P = wce @ M  (1024x2048x1024), B from int incidence
  mm_kernel<0, 1, 0><<<dim3(NE / 64, NV / 64, 1), 256, 0, stream>>>(
      wce, NV, 0, inc, NE, 0, P, NE, 0, NV, nullptr, nullptr, nullptr);
  // 8. softmax -> ap planes (bf16), s_v
  k_softmax<<<NV, 256, 0, stream>>>(P, inc, cnt, qv, se, ce, enc_w, attn_w, enc_b, ap, sv);
  // 9. Bh = (ap_h @ Mt) * G  (4 x 1024x1024x2048), bf16 out
  mm_kernel<1, 0, 1><<<dim3(NV / 64, NV / 64, 4), 256, 0, stream>>>(
      ap, NE, (long)NV * NE, Mt, NV, 0, Bh, NV, (long)NV * NV, NE, G, nullptr, nullptr);
  // 10. out_h = Bh @ Whh_h + Wh*(1 - s_v*Gvv)  (4 x 1024x64x1024)
  mm_kernel<1, 0, 2><<<dim3(1, NV / 64, 4), 256, 0, stream>>>(
      Bh, NV, (long)NV * NV, Wh, 256, 64, out, 0, 0, NV, G, Wh, sv);
  // 11. LayerNorm in place
  k_ln<<<NV, 256, 0, stream>>>(out, lng, lnb);
}

// Round 2
// 239.805 us; speedup vs baseline: 2.5610x; 2.5610x over previous
//
#include <hip/hip_runtime.h>
#include <hip/hip_bf16.h>

#define NV 1024
#define NE 2048

typedef unsigned short u16;
typedef __attribute__((ext_vector_type(8))) short bf16x8;
typedef __attribute__((ext_vector_type(4))) float f32x4;

__device__ __forceinline__ float bf2f(u16 u) { return __uint_as_float(((unsigned)u) << 16); }
__device__ __forceinline__ u16 f2bf(float f) {
  unsigned x = __float_as_uint(f);
  return (u16)((x + 0x7fffu + ((x >> 16) & 1u)) >> 16);
}
// XOR swizzle for 128-row x 64B LDS tiles: spreads the 16B quad of each row
// across all 8 bank-quads (2-way aliasing over 16 rows = free per m136).
__device__ __forceinline__ int swz(int byte) { return byte ^ (((byte >> 6) & 7) << 4); }

// ---------------------------------------------------------------------------
// bf16 MFMA GEMM: C(M,N) = A(bf16) @ B(from int incidence), tile 128x128,
// BK=32, 256 threads = 4 waves (2x2), each wave 64x64 = 4x4 frags of 16x16x32.
// BMODE 0: Bs[n][k] = inc[(n0+n)*ldb + (k0+k)] > 0   (step 9: B = M^T)
// BMODE 1: Bs[n][k] = inc[(k0+k)*ldb + (n0+n)] > 0   (step 7: B = M)
// EPI 0: f32 store (P).  EPI 1: bf16 store of acc * G[m][n] (Bh planes).
// ---------------------------------------------------------------------------
template <int BMODE, int EPI>
__global__ __launch_bounds__(256) void mfma_kernel(
    const u16* __restrict__ A, int lda, long sA,
    const int* __restrict__ incB, int ldb,
    void* __restrict__ Cp, int ldc, long sC, int K,
    const float* __restrict__ Gm) {
  __shared__ __align__(16) char As[8192];
  __shared__ __align__(16) char Bs[8192];
  const int t = threadIdx.x;
  const int m0 = blockIdx.y * 128, n0 = blockIdx.x * 128, z = blockIdx.z;
  const int wave = t >> 6, lane = t & 63;
  const int wm = (wave >> 1) * 64, wn = (wave & 1) * 64;
  const int lhi = lane >> 4, llo = lane & 15;
  const u16* Az = A + sA * z;

  f32x4 acc[4][4] = {};
  for (int k0 = 0; k0 < K; k0 += 32) {
    // stage A: 2 x 16B per thread (128 rows x 64B)
    {
      int row = t >> 2, ko = (t & 3) * 8;
      float4 v0 = *(const float4*)(Az + (long)(m0 + row) * lda + k0 + ko);
      *(float4*)(As + swz(row * 64 + ko * 2)) = v0;
      int q = t + 256;
      row = q >> 2; ko = (q & 3) * 8;
      float4 v1 = *(const float4*)(Az + (long)(m0 + row) * lda + k0 + ko);
      *(float4*)(As + swz(row * 64 + ko * 2)) = v1;
    }
    if constexpr (BMODE == 0) {
#pragma unroll
      for (int p = 0; p < 4; p++) {
        int q = t + p * 256;  // covers 128 n-rows x 8 k-quads
        int n = q >> 3, k4 = (q & 7) * 4;
        int4 b4 = *(const int4*)(incB + (long)(n0 + n) * ldb + k0 + k4);
        ushort4 w;
        w.x = b4.x > 0 ? 0x3F80 : 0;
        w.y = b4.y > 0 ? 0x3F80 : 0;
        w.z = b4.z > 0 ? 0x3F80 : 0;
        w.w = b4.w > 0 ? 0x3F80 : 0;
        *(ushort4*)(Bs + swz(n * 64 + k4 * 2)) = w;
      }
    } else {
#pragma unroll
      for (int p = 0; p < 4; p++) {
        int n = t & 127, u0 = (t >> 7) * 4 + p * 8;
        const int* bp = incB + (long)(k0 + u0) * ldb + n0 + n;
        int i0 = bp[0];
        int i1 = bp[ldb];
        int i2 = bp[2 * ldb];
        int i3 = bp[3 * ldb];
        ushort4 w;
        w.x = i0 > 0 ? 0x3F80 : 0;
        w.y = i1 > 0 ? 0x3F80 : 0;
        w.z = i2 > 0 ? 0x3F80 : 0;
        w.w = i3 > 0 ? 0x3F80 : 0;
        *(ushort4*)(Bs + swz(n * 64 + u0 * 2)) = w;
      }
    }
    __syncthreads();
    bf16x8 af[4], bfr[4];
#pragma unroll
    for (int mi = 0; mi < 4; mi++)
      af[mi] = *(const bf16x8*)(As + swz((wm + mi * 16 + llo) * 64 + lhi * 16));
#pragma unroll
    for (int ni = 0; ni < 4; ni++)
      bfr[ni] = *(const bf16x8*)(Bs + swz((wn + ni * 16 + llo) * 64 + lhi * 16));
#pragma unroll
    for (int mi = 0; mi < 4; mi++)
#pragma unroll
      for (int ni = 0; ni < 4; ni++)
        acc[mi][ni] =
            __builtin_amdgcn_mfma_f32_16x16x32_bf16(af[mi], bfr[ni], acc[mi][ni], 0, 0, 0);
    __syncthreads();
  }
#pragma unroll
  for (int mi = 0; mi < 4; mi++)
#pragma unroll
    for (int ni = 0; ni < 4; ni++)
#pragma unroll
      for (int r = 0; r < 4; r++) {
        int m = m0 + wm + mi * 16 + lhi * 4 + r;
        int n = n0 + wn + ni * 16 + llo;
        float vv = acc[mi][ni][r];
        if constexpr (EPI == 0) {
          ((float*)Cp)[(long)m * ldc + n] = vv;
        } else {
          ((u16*)Cp)[sC * z + (long)m * ldc + n] = f2bf(vv * Gm[(long)m * NV + n]);
        }
      }
}

// ---------------------------------------------------------------------------
// f32 tiled matmul (kept for steps 1 and 10). 64x64 tile, BK=16, 4x4 micro.
// TAISBF: A bf16. EPI 0: f32 store. EPI 2: attention-output epilogue.
// ---------------------------------------------------------------------------
template <int TAISBF, int EPI>
__global__ __launch_bounds__(256) void mm_kernel(
    const void* __restrict__ Ap, int lda, long sA,
    const float* __restrict__ Bp, int ldb, long sB,
    void* __restrict__ Cp, int ldc, long sC, int K,
    const float* __restrict__ Gm, const float* __restrict__ WhP,
    const float* __restrict__ svP) {
  __shared__ float As[16][68];
  __shared__ float Bs[16][68];
  const int t = threadIdx.x;
  const int tx = t & 15, ty = t >> 4;
  const int m0 = blockIdx.y * 64, n0 = blockIdx.x * 64, z = blockIdx.z;
  const int lr = t >> 2, lc4 = (t & 3) * 4;
  const int bk = t >> 4, bn = (t & 15) * 4;
  float acc[4][4] = {};
  for (int k0 = 0; k0 < K; k0 += 16) {
    if constexpr (TAISBF) {
      const u16* Az = (const u16*)Ap + sA * z;
      ushort4 a4 = *(const ushort4*)(Az + (long)(m0 + lr) * lda + k0 + lc4);
      As[lc4 + 0][lr] = bf2f(a4.x);
      As[lc4 + 1][lr] = bf2f(a4.y);
      As[lc4 + 2][lr] = bf2f(a4.z);
      As[lc4 + 3][lr] = bf2f(a4.w);
    } else {
      const float* Az = (const float*)Ap + sA * z;
      float4 a4 = *(const float4*)(Az + (long)(m0 + lr) * lda + k0 + lc4);
      As[lc4 + 0][lr] = a4.x;
      As[lc4 + 1][lr] = a4.y;
      As[lc4 + 2][lr] = a4.z;
      As[lc4 + 3][lr] = a4.w;
    }
    {
      const float* Bz = Bp + sB * z;
      float4 b4 = *(const float4*)(Bz + (long)(k0 + bk) * ldb + n0 + bn);
      Bs[bk][bn + 0] = b4.x;
      Bs[bk][bn + 1] = b4.y;
      Bs[bk][bn + 2] = b4.z;
      Bs[bk][bn + 3] = b4.w;
    }
    __syncthreads();
#pragma unroll
    for (int kk = 0; kk < 16; kk++) {
      float a[4], b[4];
      *(float4*)a = *(const float4*)&As[kk][ty * 4];
      *(float4*)b = *(const float4*)&Bs[kk][tx * 4];
#pragma unroll
      for (int i = 0; i < 4; i++)
#pragma unroll
        for (int j = 0; j < 4; j++) acc[i][j] = fmaf(a[i], b[j], acc[i][j]);
    }
    __syncthreads();
  }
#pragma unroll
  for (int i = 0; i < 4; i++) {
    const int m = m0 + ty * 4 + i;
#pragma unroll
    for (int j = 0; j < 4; j++) {
      const int n = n0 + tx * 4 + j;
      float vv = acc[i][j];
      if constexpr (EPI == 0) {
        ((float*)Cp)[sC * z + (long)m * ldc + n] = vv;
      } else {
        float w = WhP[(long)m * 256 + z * 64 + n];
        ((float*)Cp)[(long)m * 256 + z * 64 + n] =
            vv + w * (1.f - svP[m * 4 + z] * Gm[(long)m * NV + m]);
      }
    }
  }
}

// qv[v,h] = Whh[v,h,:].a_v ; qe[v,h] = Whh[v,h,:].a_e
__global__ __launch_bounds__(256) void k_qse1(const float* __restrict__ Wh,
                                              const float* __restrict__ attn_w,
                                              float* __restrict__ qv, float* __restrict__ qe) {
  int v = blockIdx.x, t = threadIdx.x;
  int d = t & 63, h = t >> 6;
  float x = Wh[(long)v * 256 + t];
  float pv = x * attn_w[d];
  float pe = x * attn_w[64 + d];
  for (int s = 32; s; s >>= 1) {
    pv += __shfl_down(pv, s);
    pe += __shfl_down(pe, s);
  }
  if (d == 0) {
    qv[v * 4 + h] = pv;
    qe[v * 4 + h] = pe;
  }
}

// Partial cnt_e and se-sums over a 32-vertex slab. part[(j*32+b)*NE + e].
__global__ __launch_bounds__(256) void k_cntse(const int* __restrict__ inc,
                                               const float* __restrict__ qe,
                                               float* __restrict__ part) {
  int e = blockIdx.x * 256 + threadIdx.x;
  int b = blockIdx.y;
  int v0 = b * 32;
  float c = 0, s0 = 0, s1 = 0, s2 = 0, s3 = 0;
  for (int v = v0; v < v0 + 32; v++) {
    if (inc[(long)v * NE + e] > 0) {
      c += 1.f;
      s0 += qe[v * 4 + 0];
      s1 += qe[v * 4 + 1];
      s2 += qe[v * 4 + 2];
      s3 += qe[v * 4 + 3];
    }
  }
  part[(0 * 32 + b) * NE + e] = c;
  part[(1 * 32 + b) * NE + e] = s0;
  part[(2 * 32 + b) * NE + e] = s1;
  part[(3 * 32 + b) * NE + e] = s2;
  part[(4 * 32 + b) * NE + e] = s3;
}

// Deterministic reduction of the 32 slabs. se holds RAW sums (div by deg in
// k_softmax).
__global__ __launch_bounds__(256) void k_sered(const float* __restrict__ part,
                                               float* __restrict__ cnt, float* __restrict__ se) {
  int e = blockIdx.x * 256 + threadIdx.x;
  int j = blockIdx.y;
  float s = 0;
  for (int b = 0; b < 32; b++) s += part[(j * 32 + b) * NE + e];
  if (j == 0)
    cnt[e] = s;
  else
    se[e * 4 + (j - 1)] = s;
}

// Per (v,u): gate G via 2->32->1 MLP, and wce (bf16) = ce . (enc_w @ a_c)
__global__ __launch_bounds__(256) void k_G(const float* __restrict__ ce,
                                           const float* __restrict__ enc_w,
                                           const float* __restrict__ attn_w,
                                           const float* __restrict__ g1w,
                                           const float* __restrict__ g1b,
                                           const float* __restrict__ g2w,
                                           const float* __restrict__ g2b,
                                           float* __restrict__ G, u16* __restrict__ wce) {
  long idx = (long)blockIdx.x * 256 + threadIdx.x;
  float2 c = *(const float2*)(ce + idx * 2);
  float ew0 = 0, ew1 = 0;
#pragma unroll
  for (int j = 0; j < 8; j++) {
    float ac = attn_w[128 + j];
    ew0 += enc_w[j] * ac;
    ew1 += enc_w[8 + j] * ac;
  }
  wce[idx] = f2bf(c.x * ew0 + c.y * ew1);
  float s = g2b[0];
#pragma unroll
  for (int j = 0; j < 32; j++) {
    float zz = fmaxf(c.x * g1w[j] + c.y * g1w[32 + j] + g1b[j], 0.f);
    s = fmaf(zz, g2w[j], s);
  }
  G[idx] = 1.f / (1.f + expf(-s));
}

// Per v: scores -> leaky_relu -> mask -> softmax over E -> ap (bf16 planes), s_v
__global__ __launch_bounds__(256) void k_softmax(
    const float* __restrict__ P, const int* __restrict__ inc, const float* __restrict__ cnt,
    const float* __restrict__ qv, const float* __restrict__ se, const float* __restrict__ ce,
    const float* __restrict__ enc_w, const float* __restrict__ attn_w,
    const float* __restrict__ enc_b, u16* __restrict__ ap, float* __restrict__ sv) {
  int v = blockIdx.x, t = threadIdx.x;
  float ew0 = 0, ew1 = 0, ebac = 0;
#pragma unroll
  for (int j = 0; j < 8; j++) {
    float ac = attn_w[128 + j];
    ew0 += enc_w[j] * ac;
    ew1 += enc_w[8 + j] * ac;
    ebac += enc_b[j] * ac;
  }
  float dce = ce[((long)v * NV + v) * 2] * ew0 + ce[((long)v * NV + v) * 2 + 1] * ew1;
  float svh[4];
#pragma unroll
  for (int hh = 0; hh < 4; hh++) svh[hh] = qv[v * 4 + hh];

  float sc[8][4];
  float invn[8], msk[8];
  float mx[4] = {-3e38f, -3e38f, -3e38f, -3e38f};
  for (int i = 0; i < 8; i++) {
    int e = t + i * 256;
    float cnte = cnt[e];
    float mask = inc[(long)v * NE + e] > 0 ? 1.f : 0.f;
    float nve = cnte - mask;
    float inv = nve > 0.f ? 1.f / nve : 0.f;
    float rdg = 1.f / fmaxf(cnte, 1.f);
    invn[i] = inv;
    msk[i] = mask;
    float cc = inv * (P[(long)v * NE + e] - mask * dce) + ebac;
#pragma unroll
    for (int hh = 0; hh < 4; hh++) {
      float s = svh[hh] + se[e * 4 + hh] * rdg + cc;
      s = s > 0.f ? s : 0.2f * s;
      s = mask > 0.f ? s : -1e9f;
      sc[i][hh] = s;
      mx[hh] = fmaxf(mx[hh], s);
    }
  }
  __shared__ float red[4][256];
#pragma unroll
  for (int hh = 0; hh < 4; hh++) red[hh][t] = mx[hh];
  __syncthreads();
  for (int s = 128; s; s >>= 1) {
    if (t < s)
#pragma unroll
      for (int hh = 0; hh < 4; hh++) red[hh][t] = fmaxf(red[hh][t], red[hh][t + s]);
    __syncthreads();
  }
  float gm[4];
#pragma unroll
  for (int hh = 0; hh < 4; hh++) gm[hh] = red[hh][0];
  __syncthreads();

  float lsum[4] = {0, 0, 0, 0};
  for (int i = 0; i < 8; i++)
#pragma unroll
    for (int hh = 0; hh < 4; hh++) {
      float p = expf(sc[i][hh] - gm[hh]);
      sc[i][hh] = p;
      lsum[hh] += p;
    }
#pragma unroll
  for (int hh = 0; hh < 4; hh++) red[hh][t] = lsum[hh];
  __syncthreads();
  for (int s = 128; s; s >>= 1) {
    if (t < s)
#pragma unroll
      for (int hh = 0; hh < 4; hh++) red[hh][t] += red[hh][t + s];
    __syncthreads();
  }
  float inv_s[4];
#pragma unroll
  for (int hh = 0; hh < 4; hh++) inv_s[hh] = 1.f / red[hh][0];
  __syncthreads();

  float lsv[4] = {0, 0, 0, 0};
  for (int i = 0; i < 8; i++) {
    int e = t + i * 256;
#pragma unroll
    for (int hh = 0; hh < 4; hh++) {
      float a = sc[i][hh] * inv_s[hh] * msk[i] * invn[i];
      ap[(long)hh * NV * NE + (long)v * NE + e] = f2bf(a);
      lsv[hh] += a;
    }
  }
#pragma unroll
  for (int hh = 0; hh < 4; hh++) red[hh][t] = lsv[hh];
  __syncthreads();
  for (int s = 128; s; s >>= 1) {
    if (t < s)
#pragma unroll
      for (int hh = 0; hh < 4; hh++) red[hh][t] += red[hh][t + s];
    __syncthreads();
  }
  if (t == 0)
#pragma unroll
    for (int hh = 0; hh < 4; hh++) sv[v * 4 + hh] = red[hh][0];
}

// LayerNorm over 256, in place
__global__ __launch_bounds__(256) void k_ln(float* __restrict__ out, const float* __restrict__ lng,
                                            const float* __restrict__ lnb) {
  int v = blockIdx.x, t = threadIdx.x;
  __shared__ float red[256];
  float x = out[(long)v * 256 + t];
  red[t] = x;
  __syncthreads();
  for (int s = 128; s; s >>= 1) {
    if (t < s) red[t] += red[t + s];
    __syncthreads();
  }
  float mu = red[0] * (1.f / 256.f);
  __syncthreads();
  float d = x - mu;
  red[t] = d * d;
  __syncthreads();
  for (int s = 128; s; s >>= 1) {
    if (t < s) red[t] += red[t + s];
    __syncthreads();
  }
  float var = red[0] * (1.f / 256.f);
  out[(long)v * 256 + t] = d / sqrtf(var + 1e-5f) * lng[t] + lnb[t];
}

extern "C" void kernel_launch(void* const* d_in, const int* in_sizes, int n_in,
                              void* d_out, int out_size, void* d_ws, size_t ws_size,
                              hipStream_t stream) {
  const float* h = (const float*)d_in[0];
  const float* ce = (const float*)d_in[1];
  const float* W = (const float*)d_in[2];
  const float* attn_w = (const float*)d_in[3];
  const float* enc_w = (const float*)d_in[4];
  const float* enc_b = (const float*)d_in[5];
  const float* g1w = (const float*)d_in[6];
  const float* g1b = (const float*)d_in[7];
  const float* g2w = (const float*)d_in[8];
  const float* g2b = (const float*)d_in[9];
  const float* lng = (const float*)d_in[10];
  const float* lnb = (const float*)d_in[11];
  const int* inc = (const int*)d_in[12];
  float* out = (float*)d_out;

  size_t off = 0;
  char* base = (char*)d_ws;
  auto alloc = [&](size_t bytes) {
    void* p = base + off;
    off += (bytes + 255) & ~(size_t)255;
    return p;
  };
  float* Wh = (float*)alloc((size_t)NV * 256 * 4);
  float* cnt = (float*)alloc((size_t)NE * 4);
  float* qv = (float*)alloc((size_t)NV * 4 * 4);
  float* qe = (float*)alloc((size_t)NV * 4 * 4);
  float* se = (float*)alloc((size_t)NE * 4 * 4);
  float* sv = (float*)alloc((size_t)NV * 4 * 4);
  float* part = (float*)alloc((size_t)5 * 32 * NE * 4);
  float* G = (float*)alloc((size_t)NV * NV * 4);
  u16* wce = (u16*)alloc((size_t)NV * NV * 2);
  float* P = (float*)alloc((size_t)NV * NE * 4);
  u16* ap = (u16*)alloc((size_t)4 * NV * NE * 2);
  u16* Bh = (u16*)alloc((size_t)4 * NV * NV * 2);
  (void)ws_size;
  (void)in_sizes;
  (void)n_in;
  (void)out_size;

  // 1. Wh = h @ W  (1024x256x256)
  mm_kernel<0, 0><<<dim3(256 / 64, NV / 64, 1), 256, 0, stream>>>(
      h, 256, 0, W, 256, 0, Wh, 256, 0, 256, nullptr, nullptr, nullptr);
  // 2. qv, qe
  k_qse1<<<NV, 256, 0, stream>>>(Wh, attn_w, qv, qe);
  // 3. cnt_e + se sums: v-split partials then deterministic reduce
  k_cntse<<<dim3(NE / 256, 32), 256, 0, stream>>>(inc, qe, part);
  k_sered<<<dim3(NE / 256, 5), 256, 0, stream>>>(part, cnt, se);
  // 4. G, wce(bf16)
  k_G<<<(NV * NV) / 256, 256, 0, stream>>>(ce, enc_w, attn_w, g1w, g1b, g2w, g2b, G, wce);
  // 5. P = wce @ M  (1024x2048, K=1024) via MFMA, B staged transposed from inc
  mfma_kernel<1, 0><<<dim3(NE / 128, NV / 128, 1), 256, 0, stream>>>(
      wce, NV, 0, inc, NE, P, NE, 0, NV, nullptr);
  // 6. softmax -> ap planes (bf16), s_v
  k_softmax<<<NV, 256, 0, stream>>>(P, inc, cnt, qv, se, ce, enc_w, attn_w, enc_b, ap, sv);
  // 7. Bh = (ap_h @ M^T) * G  (4 x 1024x1024, K=2048) via MFMA, B from inc rows
  mfma_kernel<0, 1><<<dim3(NV / 128, NV / 128, 4), 256, 0, stream>>>(
      ap, NE, (long)NV * NE, inc, NE, Bh, NV, (long)NV * NV, NE, G);
  // 8. out_h = Bh @ Whh_h + Wh*(1 - s_v*Gvv)  (4 x 1024x64, K=1024)
  mm_kernel<1, 2><<<dim3(1, NV / 64, 4), 256, 0, stream>>>(
      Bh, NV, (long)NV * NV, Wh, 256, 64, out, 0, 0, NV, G, Wh, sv);
  // 9. LayerNorm in place
  k_ln<<<NV, 256, 0, stream>>>(out, lng, lnb);
}

// Round 3
// 162.882 us; speedup vs baseline: 3.7704x; 1.4723x over previous
//
#include <hip/hip_runtime.h>
#include <hip/hip_bf16.h>

#define NV 1024
#define NE 2048

typedef unsigned short u16;
typedef __attribute__((ext_vector_type(8))) short bf16x8;
typedef __attribute__((ext_vector_type(4))) float f32x4;

__device__ __forceinline__ float bf2f(u16 u) { return __uint_as_float(((unsigned)u) << 16); }
__device__ __forceinline__ u16 f2bf(float f) {
  unsigned x = __float_as_uint(f);
  return (u16)((x + 0x7fffu + ((x >> 16) & 1u)) >> 16);
}

// async global->LDS, 16B per lane, wave-uniform LDS base + lane*16
#define GLL(src, dst)                                                        \
  __builtin_amdgcn_global_load_lds(                                          \
      (const __attribute__((address_space(1))) void*)(src),                  \
      (__attribute__((address_space(3))) void*)(dst), 16, 0, 0)

// ---------------------------------------------------------------------------
// bt-GEMM (m97 structure): C(M,N) = A @ BT^T, A row-major [M][K] bf16,
// BT row-major [N][K] bf16. 128x128 tile, BK=32, 4 waves (2x2), each wave
// 64x64 = 4x4 frags of 16x16x32. Staging via global_load_lds width 16,
// linear LDS [128 rows][64 B].
// EPI 0: f32 store. EPI 1: bf16 store of acc * Gm[m][n].
// ---------------------------------------------------------------------------
template <int EPI>
__global__ __launch_bounds__(256) void mfma_bt(
    const u16* __restrict__ A, int lda, long sA,
    const u16* __restrict__ BT, int ldb, long sBT,
    void* __restrict__ Cp, int ldc, long sC, int K,
    const float* __restrict__ Gm) {
  __shared__ __align__(16) char As[8192];
  __shared__ __align__(16) char Bs[8192];
  const int t = threadIdx.x;
  const int m0 = blockIdx.y * 128, n0 = blockIdx.x * 128, z = blockIdx.z;
  const int wave = t >> 6, lane = t & 63;
  const int lhi = lane >> 4, llo = lane & 15;
  const int wm = (wave >> 1) * 64, wn = (wave & 1) * 64;
  const char* Ab = (const char*)(A + sA * z);
  const char* Bb = (const char*)(BT + sBT * z);
  const long lda2 = (long)lda * 2, ldb2 = (long)ldb * 2;
  const int rowA = t >> 2, colA = (t & 3) * 16;  // within a 64-row half
  char* la0 = As + ((t >> 6) << 10);
  char* lb0 = Bs + ((t >> 6) << 10);

  f32x4 acc[4][4] = {};
  for (int k0 = 0; k0 < K; k0 += 32) {
    const long kb = (long)k0 * 2 + colA;
    GLL(Ab + (long)(m0 + rowA) * lda2 + kb, la0);
    GLL(Ab + (long)(m0 + 64 + rowA) * lda2 + kb, la0 + 4096);
    GLL(Bb + (long)(n0 + rowA) * ldb2 + kb, lb0);
    GLL(Bb + (long)(n0 + 64 + rowA) * ldb2 + kb, lb0 + 4096);
    __syncthreads();
    bf16x8 af[4], bf[4];
#pragma unroll
    for (int mi = 0; mi < 4; mi++)
      af[mi] = *(const bf16x8*)(As + (wm + mi * 16 + llo) * 64 + lhi * 16);
#pragma unroll
    for (int ni = 0; ni < 4; ni++)
      bf[ni] = *(const bf16x8*)(Bs + (wn + ni * 16 + llo) * 64 + lhi * 16);
#pragma unroll
    for (int mi = 0; mi < 4; mi++)
#pragma unroll
      for (int ni = 0; ni < 4; ni++)
        acc[mi][ni] =
            __builtin_amdgcn_mfma_f32_16x16x32_bf16(af[mi], bf[ni], acc[mi][ni], 0, 0, 0);
    __syncthreads();
  }
#pragma unroll
  for (int mi = 0; mi < 4; mi++)
#pragma unroll
    for (int ni = 0; ni < 4; ni++)
#pragma unroll
      for (int r = 0; r < 4; r++) {
        int m = m0 + wm + mi * 16 + lhi * 4 + r;
        int n = n0 + wn + ni * 16 + llo;
        float vv = acc[mi][ni][r];
        if constexpr (EPI == 0) {
          ((float*)Cp)[sC * z + (long)m * ldc + n] = vv;
        } else {
          ((u16*)Cp)[sC * z + (long)m * ldc + n] = f2bf(vv * Gm[(long)m * NV + n]);
        }
      }
}

// ---------------------------------------------------------------------------
// Step 8: out_h = Bh_h @ Whh_h + residual. Tile 128(m) x 64(n), BK=32,
// 4 waves (2m x 2n), wave-tile 64x32 = 4x2 frags. BT = Whht rows (d, ldb=NV).
// ---------------------------------------------------------------------------
__global__ __launch_bounds__(256) void mfma_out(
    const u16* __restrict__ Bh, const u16* __restrict__ Whht,
    const float* __restrict__ WhF, const float* __restrict__ G,
    const float* __restrict__ sv, float* __restrict__ out) {
  __shared__ __align__(16) char As[8192];
  __shared__ __align__(16) char Bs[4096];
  const int t = threadIdx.x, z = blockIdx.z, m0 = blockIdx.y * 128;
  const int wave = t >> 6, lane = t & 63;
  const int lhi = lane >> 4, llo = lane & 15;
  const int wm = (wave >> 1) * 64, wn = (wave & 1) * 32;
  const char* Ab = (const char*)(Bh + (long)z * NV * NV);
  const char* Bb = (const char*)(Whht + (long)z * 64 * NV);
  const int rowA = t >> 2, colA = (t & 3) * 16;
  char* la0 = As + ((t >> 6) << 10);
  char* lb0 = Bs + ((t >> 6) << 10);

  f32x4 acc[4][2] = {};
  for (int k0 = 0; k0 < NV; k0 += 32) {
    const long kb = (long)k0 * 2 + colA;
    GLL(Ab + (long)(m0 + rowA) * (NV * 2) + kb, la0);
    GLL(Ab + (long)(m0 + 64 + rowA) * (NV * 2) + kb, la0 + 4096);
    GLL(Bb + (long)rowA * (NV * 2) + kb, lb0);
    __syncthreads();
    bf16x8 af[4], bf[2];
#pragma unroll
    for (int mi = 0; mi < 4; mi++)
      af[mi] = *(const bf16x8*)(As + (wm + mi * 16 + llo) * 64 + lhi * 16);
#pragma unroll
    for (int ni = 0; ni < 2; ni++)
      bf[ni] = *(const bf16x8*)(Bs + (wn + ni * 16 + llo) * 64 + lhi * 16);
#pragma unroll
    for (int mi = 0; mi < 4; mi++)
#pragma unroll
      for (int ni = 0; ni < 2; ni++)
        acc[mi][ni] =
            __builtin_amdgcn_mfma_f32_16x16x32_bf16(af[mi], bf[ni], acc[mi][ni], 0, 0, 0);
    __syncthreads();
  }
#pragma unroll
  for (int mi = 0; mi < 4; mi++)
#pragma unroll
    for (int r = 0; r < 4; r++) {
      int m = m0 + wm + mi * 16 + lhi * 4 + r;
      float corr = 1.f - sv[m * 4 + z] * G[(long)m * NV + m];
#pragma unroll
      for (int ni = 0; ni < 2; ni++) {
        int n = wn + ni * 16 + llo;
        long o = (long)m * 256 + z * 64 + n;
        out[o] = acc[mi][ni][r] + WhF[o] * corr;
      }
    }
}

// ---------------------------------------------------------------------------
// f32 tiled matmul for step 1 only (Wh = h @ W). 64x64 tile, BK=16.
// ---------------------------------------------------------------------------
__global__ __launch_bounds__(256) void mm_f32(
    const float* __restrict__ Ap, const float* __restrict__ Bp,
    float* __restrict__ Cp) {
  __shared__ float As[16][68];
  __shared__ float Bs[16][68];
  const int t = threadIdx.x;
  const int tx = t & 15, ty = t >> 4;
  const int m0 = blockIdx.y * 64, n0 = blockIdx.x * 64;
  const int lr = t >> 2, lc4 = (t & 3) * 4;
  const int bk = t >> 4, bn = (t & 15) * 4;
  float acc[4][4] = {};
  for (int k0 = 0; k0 < 256; k0 += 16) {
    float4 a4 = *(const float4*)(Ap + (long)(m0 + lr) * 256 + k0 + lc4);
    As[lc4 + 0][lr] = a4.x;
    As[lc4 + 1][lr] = a4.y;
    As[lc4 + 2][lr] = a4.z;
    As[lc4 + 3][lr] = a4.w;
    float4 b4 = *(const float4*)(Bp + (long)(k0 + bk) * 256 + n0 + bn);
    Bs[bk][bn + 0] = b4.x;
    Bs[bk][bn + 1] = b4.y;
    Bs[bk][bn + 2] = b4.z;
    Bs[bk][bn + 3] = b4.w;
    __syncthreads();
#pragma unroll
    for (int kk = 0; kk < 16; kk++) {
      float a[4], b[4];
      *(float4*)a = *(const float4*)&As[kk][ty * 4];
      *(float4*)b = *(const float4*)&Bs[kk][tx * 4];
#pragma unroll
      for (int i = 0; i < 4; i++)
#pragma unroll
        for (int j = 0; j < 4; j++) acc[i][j] = fmaf(a[i], b[j], acc[i][j]);
    }
    __syncthreads();
  }
#pragma unroll
  for (int i = 0; i < 4; i++)
#pragma unroll
    for (int j = 0; j < 4; j++)
      Cp[(long)(m0 + ty * 4 + i) * 256 + n0 + tx * 4 + j] = acc[i][j];
}

// Build Mbf[v][e] (bf16 1/0) and Mtbf[e][v] via LDS-tiled transpose.
__global__ __launch_bounds__(256) void k_conv(const int* __restrict__ inc,
                                              u16* __restrict__ Mbf,
                                              u16* __restrict__ Mtbf) {
  __shared__ u16 tile[64][65];
  const int e0 = blockIdx.x * 64, v0 = blockIdx.y * 64;
  const int t = threadIdx.x;
#pragma unroll
  for (int p = 0; p < 4; p++) {
    int r = p * 16 + (t >> 4);
    int c4 = (t & 15) * 4;
    int4 q = *(const int4*)(inc + (long)(v0 + r) * NE + e0 + c4);
    ushort4 w;
    w.x = q.x > 0 ? 0x3F80 : 0;
    w.y = q.y > 0 ? 0x3F80 : 0;
    w.z = q.z > 0 ? 0x3F80 : 0;
    w.w = q.w > 0 ? 0x3F80 : 0;
    *(ushort4*)&Mbf[(long)(v0 + r) * NE + e0 + c4] = w;
    tile[c4 + 0][r] = w.x;
    tile[c4 + 1][r] = w.y;
    tile[c4 + 2][r] = w.z;
    tile[c4 + 3][r] = w.w;
  }
  __syncthreads();
#pragma unroll
  for (int p = 0; p < 4; p++) {
    int er = p * 16 + (t >> 4);
    int vc4 = (t & 15) * 4;
    ushort4 w;
    w.x = tile[er][vc4 + 0];
    w.y = tile[er][vc4 + 1];
    w.z = tile[er][vc4 + 2];
    w.w = tile[er][vc4 + 3];
    *(ushort4*)&Mtbf[(long)(e0 + er) * NV + v0 + vc4] = w;
  }
}

// Whht[c][u] = bf16(Wh[u][c]) — transpose to [256][1024] bf16
__global__ __launch_bounds__(256) void k_trw(const float* __restrict__ Wh,
                                             u16* __restrict__ Whht) {
  __shared__ u16 tile[64][65];
  const int c0 = blockIdx.x * 64, v0 = blockIdx.y * 64;
  const int t = threadIdx.x;
#pragma unroll
  for (int p = 0; p < 4; p++) {
    int r = p * 16 + (t >> 4);
    int c4 = (t & 15) * 4;
    float4 q = *(const float4*)(Wh + (long)(v0 + r) * 256 + c0 + c4);
    tile[c4 + 0][r] = f2bf(q.x);
    tile[c4 + 1][r] = f2bf(q.y);
    tile[c4 + 2][r] = f2bf(q.z);
    tile[c4 + 3][r] = f2bf(q.w);
  }
  __syncthreads();
#pragma unroll
  for (int p = 0; p < 4; p++) {
    int cr = p * 16 + (t >> 4);
    int vc4 = (t & 15) * 4;
    ushort4 w;
    w.x = tile[cr][vc4 + 0];
    w.y = tile[cr][vc4 + 1];
    w.z = tile[cr][vc4 + 2];
    w.w = tile[cr][vc4 + 3];
    *(ushort4*)&Whht[(long)(c0 + cr) * NV + v0 + vc4] = w;
  }
}

// qv[v,h] = Whh[v,h,:].a_v ; qe[v,h] = Whh[v,h,:].a_e
__global__ __launch_bounds__(256) void k_qse1(const float* __restrict__ Wh,
                                              const float* __restrict__ attn_w,
                                              float* __restrict__ qv, float* __restrict__ qe) {
  int v = blockIdx.x, t = threadIdx.x;
  int d = t & 63, h = t >> 6;
  float x = Wh[(long)v * 256 + t];
  float pv = x * attn_w[d];
  float pe = x * attn_w[64 + d];
  for (int s = 32; s; s >>= 1) {
    pv += __shfl_down(pv, s);
    pe += __shfl_down(pe, s);
  }
  if (d == 0) {
    qv[v * 4 + h] = pv;
    qe[v * 4 + h] = pe;
  }
}

// Partial cnt_e and se-sums over a 32-vertex slab.
__global__ __launch_bounds__(256) void k_cntse(const int* __restrict__ inc,
                                               const float* __restrict__ qe,
                                               float* __restrict__ part) {
  int e = blockIdx.x * 256 + threadIdx.x;
  int b = blockIdx.y;
  int v0 = b * 32;
  float c = 0, s0 = 0, s1 = 0, s2 = 0, s3 = 0;
  for (int v = v0; v < v0 + 32; v++) {
    if (inc[(long)v * NE + e] > 0) {
      c += 1.f;
      s0 += qe[v * 4 + 0];
      s1 += qe[v * 4 + 1];
      s2 += qe[v * 4 + 2];
      s3 += qe[v * 4 + 3];
    }
  }
  part[(0 * 32 + b) * NE + e] = c;
  part[(1 * 32 + b) * NE + e] = s0;
  part[(2 * 32 + b) * NE + e] = s1;
  part[(3 * 32 + b) * NE + e] = s2;
  part[(4 * 32 + b) * NE + e] = s3;
}

// Deterministic reduction of the 32 slabs. se holds RAW sums.
__global__ __launch_bounds__(256) void k_sered(const float* __restrict__ part,
                                               float* __restrict__ cnt, float* __restrict__ se) {
  int e = blockIdx.x * 256 + threadIdx.x;
  int j = blockIdx.y;
  float s = 0;
  for (int b = 0; b < 32; b++) s += part[(j * 32 + b) * NE + e];
  if (j == 0)
    cnt[e] = s;
  else
    se[e * 4 + (j - 1)] = s;
}

// Per (v,u): gate G via 2->32->1 MLP, and wce (bf16) = ce . (enc_w @ a_c)
__global__ __launch_bounds__(256) void k_G(const float* __restrict__ ce,
                                           const float* __restrict__ enc_w,
                                           const float* __restrict__ attn_w,
                                           const float* __restrict__ g1w,
                                           const float* __restrict__ g1b,
                                           const float* __restrict__ g2w,
                                           const float* __restrict__ g2b,
                                           float* __restrict__ G, u16* __restrict__ wce) {
  long idx = (long)blockIdx.x * 256 + threadIdx.x;
  float2 c = *(const float2*)(ce + idx * 2);
  float ew0 = 0, ew1 = 0;
#pragma unroll
  for (int j = 0; j < 8; j++) {
    float ac = attn_w[128 + j];
    ew0 += enc_w[j] * ac;
    ew1 += enc_w[8 + j] * ac;
  }
  wce[idx] = f2bf(c.x * ew0 + c.y * ew1);
  float s = g2b[0];
#pragma unroll
  for (int j = 0; j < 32; j++) {
    float zz = fmaxf(c.x * g1w[j] + c.y * g1w[32 + j] + g1b[j], 0.f);
    s = fmaf(zz, g2w[j], s);
  }
  G[idx] = 1.f / (1.f + expf(-s));
}

// Per v: scores -> leaky_relu -> mask -> softmax over E -> ap (bf16 planes), s_v
__global__ __launch_bounds__(256) void k_softmax(
    const float* __restrict__ P, const int* __restrict__ inc, const float* __restrict__ cnt,
    const float* __restrict__ qv, const float* __restrict__ se, const float* __restrict__ ce,
    const float* __restrict__ enc_w, const float* __restrict__ attn_w,
    const float* __restrict__ enc_b, u16* __restrict__ ap, float* __restrict__ sv) {
  int v = blockIdx.x, t = threadIdx.x;
  float ew0 = 0, ew1 = 0, ebac = 0;
#pragma unroll
  for (int j = 0; j < 8; j++) {
    float ac = attn_w[128 + j];
    ew0 += enc_w[j] * ac;
    ew1 += enc_w[8 + j] * ac;
    ebac += enc_b[j] * ac;
  }
  float dce = ce[((long)v * NV + v) * 2] * ew0 + ce[((long)v * NV + v) * 2 + 1] * ew1;
  float svh[4];
#pragma unroll
  for (int hh = 0; hh < 4; hh++) svh[hh] = qv[v * 4 + hh];

  float sc[8][4];
  float invn[8], msk[8];
  float mx[4] = {-3e38f, -3e38f, -3e38f, -3e38f};
  for (int i = 0; i < 8; i++) {
    int e = t + i * 256;
    float cnte = cnt[e];
    float mask = inc[(long)v * NE + e] > 0 ? 1.f : 0.f;
    float nve = cnte - mask;
    float inv = nve > 0.f ? 1.f / nve : 0.f;
    float rdg = 1.f / fmaxf(cnte, 1.f);
    invn[i] = inv;
    msk[i] = mask;
    float cc = inv * (P[(long)v * NE + e] - mask * dce) + ebac;
#pragma unroll
    for (int hh = 0; hh < 4; hh++) {
      float s = svh[hh] + se[e * 4 + hh] * rdg + cc;
      s = s > 0.f ? s : 0.2f * s;
      s = mask > 0.f ? s : -1e9f;
      sc[i][hh] = s;
      mx[hh] = fmaxf(mx[hh], s);
    }
  }
  __shared__ float red[4][256];
#pragma unroll
  for (int hh = 0; hh < 4; hh++) red[hh][t] = mx[hh];
  __syncthreads();
  for (int s = 128; s; s >>= 1) {
    if (t < s)
#pragma unroll
      for (int hh = 0; hh < 4; hh++) red[hh][t] = fmaxf(red[hh][t], red[hh][t + s]);
    __syncthreads();
  }
  float gm[4];
#pragma unroll
  for (int hh = 0; hh < 4; hh++) gm[hh] = red[hh][0];
  __syncthreads();

  float lsum[4] = {0, 0, 0, 0};
  for (int i = 0; i < 8; i++)
#pragma unroll
    for (int hh = 0; hh < 4; hh++) {
      float p = expf(sc[i][hh] - gm[hh]);
      sc[i][hh] = p;
      lsum[hh] += p;
    }
#pragma unroll
  for (int hh = 0; hh < 4; hh++) red[hh][t] = lsum[hh];
  __syncthreads();
  for (int s = 128; s; s >>= 1) {
    if (t < s)
#pragma unroll
      for (int hh = 0; hh < 4; hh++) red[hh][t] += red[hh][t + s];
    __syncthreads();
  }
  float inv_s[4];
#pragma unroll
  for (int hh = 0; hh < 4; hh++) inv_s[hh] = 1.f / red[hh][0];
  __syncthreads();

  float lsv[4] = {0, 0, 0, 0};
  for (int i = 0; i < 8; i++) {
    int e = t + i * 256;
#pragma unroll
    for (int hh = 0; hh < 4; hh++) {
      float a = sc[i][hh] * inv_s[hh] * msk[i] * invn[i];
      ap[(long)hh * NV * NE + (long)v * NE + e] = f2bf(a);
      lsv[hh] += a;
    }
  }
#pragma unroll
  for (int hh = 0; hh < 4; hh++) red[hh][t] = lsv[hh];
  __syncthreads();
  for (int s = 128; s; s >>= 1) {
    if (t < s)
#pragma unroll
      for (int hh = 0; hh < 4; hh++) red[hh][t] += red[hh][t + s];
    __syncthreads();
  }
  if (t == 0)
#pragma unroll
    for (int hh = 0; hh < 4; hh++) sv[v * 4 + hh] = red[hh][0];
}

// LayerNorm over 256, in place
__global__ __launch_bounds__(256) void k_ln(float* __restrict__ out, const float* __restrict__ lng,
                                            const float* __restrict__ lnb) {
  int v = blockIdx.x, t = threadIdx.x;
  __shared__ float red[256];
  float x = out[(long)v * 256 + t];
  red[t] = x;
  __syncthreads();
  for (int s = 128; s; s >>= 1) {
    if (t < s) red[t] += red[t + s];
    __syncthreads();
  }
  float mu = red[0] * (1.f / 256.f);
  __syncthreads();
  float d = x - mu;
  red[t] = d * d;
  __syncthreads();
  for (int s = 128; s; s >>= 1) {
    if (t < s) red[t] += red[t + s];
    __syncthreads();
  }
  float var = red[0] * (1.f / 256.f);
  out[(long)v * 256 + t] = d / sqrtf(var + 1e-5f) * lng[t] + lnb[t];
}

extern "C" void kernel_launch(void* const* d_in, const int* in_sizes, int n_in,
                              void* d_out, int out_size, void* d_ws, size_t ws_size,
                              hipStream_t stream) {
  const float* h = (const float*)d_in[0];
  const float* ce = (const float*)d_in[1];
  const float* W = (const float*)d_in[2];
  const float* attn_w = (const float*)d_in[3];
  const float* enc_w = (const float*)d_in[4];
  const float* enc_b = (const float*)d_in[5];
  const float* g1w = (const float*)d_in[6];
  const float* g1b = (const float*)d_in[7];
  const float* g2w = (const float*)d_in[8];
  const float* g2b = (const float*)d_in[9];
  const float* lng = (const float*)d_in[10];
  const float* lnb = (const float*)d_in[11];
  const int* inc = (const int*)d_in[12];
  float* out = (float*)d_out;

  size_t off = 0;
  char* base = (char*)d_ws;
  auto alloc = [&](size_t bytes) {
    void* p = base + off;
    off += (bytes + 255) & ~(size_t)255;
    return p;
  };
  float* Wh = (float*)alloc((size_t)NV * 256 * 4);
  float* cnt = (float*)alloc((size_t)NE * 4);
  float* qv = (float*)alloc((size_t)NV * 4 * 4);
  float* qe = (float*)alloc((size_t)NV * 4 * 4);
  float* se = (float*)alloc((size_t)NE * 4 * 4);
  float* sv = (float*)alloc((size_t)NV * 4 * 4);
  float* G = (float*)alloc((size_t)NV * NV * 4);
  u16* wce = (u16*)alloc((size_t)NV * NV * 2);
  u16* Mbf = (u16*)alloc((size_t)NV * NE * 2);
  u16* Whht = (u16*)alloc((size_t)256 * NV * 2);
  float* P = (float*)alloc((size_t)NV * NE * 4);
  u16* ap = (u16*)alloc((size_t)4 * NV * NE * 2);
  u16* Bh = (u16*)alloc((size_t)4 * NV * NV * 2);
  // aliases (lifetimes don't overlap):
  float* part = P;                 // part (1.25MB) dead before P is written
  u16* Mtbf = Bh;                  // Mtbf (4MB) dead before Bh is written
  (void)ws_size;
  (void)in_sizes;
  (void)n_in;
  (void)out_size;

  // 0. bf16 incidence (row-major + transposed)
  k_conv<<<dim3(NE / 64, NV / 64), 256, 0, stream>>>(inc, Mbf, Mtbf);
  // 1. Wh = h @ W (f32)
  mm_f32<<<dim3(256 / 64, NV / 64), 256, 0, stream>>>(h, W, Wh);
  // 1b. Whht = Wh^T bf16
  k_trw<<<dim3(256 / 64, NV / 64), 256, 0, stream>>>(Wh, Whht);
  // 2. qv, qe
  k_qse1<<<NV, 256, 0, stream>>>(Wh, attn_w, qv, qe);
  // 3. cnt_e + se sums
  k_cntse<<<dim3(NE / 256, 32), 256, 0, stream>>>(inc, qe, part);
  k_sered<<<dim3(NE / 256, 5), 256, 0, stream>>>(part, cnt, se);
  // 4. G, wce(bf16)
  k_G<<<(NV * NV) / 256, 256, 0, stream>>>(ce, enc_w, attn_w, g1w, g1b, g2w, g2b, G, wce);
  // 5. P = wce @ M (M=1024, N=2048, K=1024), BT = Mtbf
  mfma_bt<0><<<dim3(NE / 128, NV / 128, 1), 256, 0, stream>>>(
      wce, NV, 0, Mtbf, NV, 0, P, NE, 0, NV, nullptr);
  // 6. softmax -> ap planes (bf16), s_v
  k_softmax<<<NV, 256, 0, stream>>>(P, inc, cnt, qv, se, ce, enc_w, attn_w, enc_b, ap, sv);
  // 7. Bh = (ap_h @ M^T) * G (4 x M=N=1024, K=2048), BT = Mbf
  mfma_bt<1><<<dim3(NV / 128, NV / 128, 4), 256, 0, stream>>>(
      ap, NE, (long)NV * NE, Mbf, NE, 0, Bh, NV, (long)NV * NV, NE, G);
  // 8. out_h = Bh @ Whh_h + Wh*(1 - s_v*Gvv)
  mfma_out<<<dim3(1, NV / 128, 4), 256, 0, stream>>>(Bh, Whht, Wh, G, sv, out);
  // 9. LayerNorm in place
  k_ln<<<NV, 256, 0, stream>>>(out, lng, lnb);
}

// Round 5
// 135.437 us; speedup vs baseline: 4.5345x; 1.2026x over previous
//
#include <hip/hip_runtime.h>
#include <hip/hip_bf16.h>

#define NV 1024
#define NE 2048

typedef unsigned short u16;
typedef __attribute__((ext_vector_type(8))) short bf16x8;
typedef __attribute__((ext_vector_type(4))) float f32x4;

__device__ __forceinline__ float bf2f(u16 u) { return __uint_as_float(((unsigned)u) << 16); }
__device__ __forceinline__ u16 f2bf(float f) {
  unsigned x = __float_as_uint(f);
  return (u16)((x + 0x7fffu + ((x >> 16) & 1u)) >> 16);
}

// async global->LDS, 16B per lane, wave-uniform LDS base + lane*16
#define GLL(src, dst)                                                        \
  __builtin_amdgcn_global_load_lds(                                          \
      (const __attribute__((address_space(1))) void*)(src),                  \
      (__attribute__((address_space(3))) void*)(dst), 16, 0, 0)

// Swizzled LDS layout: logical byte L (row*64 + q*16) lives at physical byte
// P = L ^ (((L>>6)&7)<<4). Bijective (upper-triangular over GF(2)). A
// fragment read (16 consecutive rows, fixed q) then touches all 8 16B slots
// -> 2-way bank aliasing = free. global_load_lds writes LINEAR physical
// positions, so the per-lane GLOBAL SOURCE is permuted by the inverse map
// (rule #21: both-sides-or-neither).
__device__ __forceinline__ void invswz(int g, int& row, int& kq) {
  int pb = g * 16;
  int lb = pb ^ ((((pb >> 8) & 1) << 6) | (((pb >> 7) & 1) << 5) |
                 ((((pb >> 6) ^ (pb >> 8)) & 1) << 4));
  row = lb >> 6;
  kq = lb & 63;
}
__device__ __forceinline__ int fwdswz(int la) { return la ^ (((la >> 6) & 7) << 4); }

// ---------------------------------------------------------------------------
// bt-GEMM: C(M,N) = A @ BT^T, A row-major [M][K] bf16, BT row-major [N][K]
// bf16. Tile BM x BN, BK=32, 4 waves (2x2), wave-tile (BM/2)x(BN/2), frags
// 16x16x32. Staging via global_load_lds(16) with pre-swizzled source.
// EPI 0: f32 store. EPI 1: bf16 store of acc * Gm[m][n].
// EPI 2: split-K f32 partial for the output GEMM (blockIdx.z = z*8 + ks,
//        K=128 slice, store part[ks][m][z*64+n]).
// ---------------------------------------------------------------------------
template <int BM, int BN, int EPI>
__global__ __launch_bounds__(256) void mfma_bt(
    const u16* __restrict__ A, int lda, long sA,
    const u16* __restrict__ BT, int ldb, long sBT,
    void* __restrict__ Cp, int ldc, long sC, int K,
    const float* __restrict__ Gm) {
  constexpr int FM = BM / 32, FN = BN / 32;
  __shared__ __align__(16) char As[BM * 64];
  __shared__ __align__(16) char Bs[BN * 64];
  const int t = threadIdx.x;
  const int wave = t >> 6, lane = t & 63;
  const int lhi = lane >> 4, llo = lane & 15;
  const int wm = (wave >> 1) * (BM / 2), wn = (wave & 1) * (BN / 2);
  const int m0 = blockIdx.y * BM, n0 = blockIdx.x * BN;
  int zz = blockIdx.z, ks = 0;
  const char* Ab;
  const char* Bb;
  if constexpr (EPI == 2) {
    zz = blockIdx.z >> 3;
    ks = blockIdx.z & 7;
    Ab = (const char*)(A + sA * zz + ks * 128);
    Bb = (const char*)(BT + sBT * zz + ks * 128);
  } else {
    Ab = (const char*)(A + sA * zz);
    Bb = (const char*)(BT + sBT * zz);
  }
  const long lda2 = (long)lda * 2, ldb2 = (long)ldb * 2;

  // precompute inverse-swizzled (row, byte-in-row) per staging granule
  int rA0, qA0, rA1, qA1, rB0, qB0;
  invswz(t, rA0, qA0);
  invswz(t + 256, rA1, qA1);
  rB0 = rA0; qB0 = qA0;
  const int wofs = (t & 192) * 16;

  f32x4 acc[FM][FN] = {};
  for (int k0 = 0; k0 < K; k0 += 32) {
    const long kb = (long)k0 * 2;
    GLL(Ab + (long)(m0 + rA0) * lda2 + kb + qA0, As + wofs);
    if constexpr (BM == 128) GLL(Ab + (long)(m0 + rA1) * lda2 + kb + qA1, As + 4096 + wofs);
    GLL(Bb + (long)(n0 + rB0) * ldb2 + kb + qB0, Bs + wofs);
    if constexpr (BN == 128) GLL(Bb + (long)(n0 + rA1) * ldb2 + kb + qA1, Bs + 4096 + wofs);
    __syncthreads();
    bf16x8 af[FM], bfv[FN];
#pragma unroll
    for (int mi = 0; mi < FM; mi++) {
      int la = (wm + mi * 16 + llo) * 64 + lhi * 16;
      af[mi] = *(const bf16x8*)(As + fwdswz(la));
    }
#pragma unroll
    for (int ni = 0; ni < FN; ni++) {
      int la = (wn + ni * 16 + llo) * 64 + lhi * 16;
      bfv[ni] = *(const bf16x8*)(Bs + fwdswz(la));
    }
#pragma unroll
    for (int mi = 0; mi < FM; mi++)
#pragma unroll
      for (int ni = 0; ni < FN; ni++)
        acc[mi][ni] =
            __builtin_amdgcn_mfma_f32_16x16x32_bf16(af[mi], bfv[ni], acc[mi][ni], 0, 0, 0);
    __syncthreads();
  }
#pragma unroll
  for (int mi = 0; mi < FM; mi++)
#pragma unroll
    for (int ni = 0; ni < FN; ni++)
#pragma unroll
      for (int r = 0; r < 4; r++) {
        int m = m0 + wm + mi * 16 + lhi * 4 + r;
        int n = n0 + wn + ni * 16 + llo;
        float vv = acc[mi][ni][r];
        if constexpr (EPI == 0) {
          ((float*)Cp)[sC * zz + (long)m * ldc + n] = vv;
        } else if constexpr (EPI == 1) {
          ((u16*)Cp)[sC * zz + (long)m * ldc + n] = f2bf(vv * Gm[(long)m * NV + n]);
        } else {
          ((float*)Cp)[(long)ks * (NV * 256) + (long)m * 256 + zz * 64 + n] = vv;
        }
      }
}

// ---------------------------------------------------------------------------
// f32 tiled matmul for step 1 only (Wh = h @ W). 64x64 tile, BK=16.
// ---------------------------------------------------------------------------
__global__ __launch_bounds__(256) void mm_f32(
    const float* __restrict__ Ap, const float* __restrict__ Bp,
    float* __restrict__ Cp) {
  __shared__ float As[16][68];
  __shared__ float Bs[16][68];
  const int t = threadIdx.x;
  const int tx = t & 15, ty = t >> 4;
  const int m0 = blockIdx.y * 64, n0 = blockIdx.x * 64;
  const int lr = t >> 2, lc4 = (t & 3) * 4;
  const int bk = t >> 4, bn = (t & 15) * 4;
  float acc[4][4] = {};
  for (int k0 = 0; k0 < 256; k0 += 16) {
    float4 a4 = *(const float4*)(Ap + (long)(m0 + lr) * 256 + k0 + lc4);
    As[lc4 + 0][lr] = a4.x;
    As[lc4 + 1][lr] = a4.y;
    As[lc4 + 2][lr] = a4.z;
    As[lc4 + 3][lr] = a4.w;
    float4 b4 = *(const float4*)(Bp + (long)(k0 + bk) * 256 + n0 + bn);
    Bs[bk][bn + 0] = b4.x;
    Bs[bk][bn + 1] = b4.y;
    Bs[bk][bn + 2] = b4.z;
    Bs[bk][bn + 3] = b4.w;
    __syncthreads();
#pragma unroll
    for (int kk = 0; kk < 16; kk++) {
      float a[4], b[4];
      *(float4*)a = *(const float4*)&As[kk][ty * 4];
      *(float4*)b = *(const float4*)&Bs[kk][tx * 4];
#pragma unroll
      for (int i = 0; i < 4; i++)
#pragma unroll
        for (int j = 0; j < 4; j++) acc[i][j] = fmaf(a[i], b[j], acc[i][j]);
    }
    __syncthreads();
  }
#pragma unroll
  for (int i = 0; i < 4; i++)
#pragma unroll
    for (int j = 0; j < 4; j++)
      Cp[(long)(m0 + ty * 4 + i) * 256 + n0 + tx * 4 + j] = acc[i][j];
}

// Build Mbf[v][e] (bf16 1/0) and Mtbf[e][v] via LDS-tiled transpose.
__global__ __launch_bounds__(256) void k_conv(const int* __restrict__ inc,
                                              u16* __restrict__ Mbf,
                                              u16* __restrict__ Mtbf) {
  __shared__ u16 tile[64][65];
  const int e0 = blockIdx.x * 64, v0 = blockIdx.y * 64;
  const int t = threadIdx.x;
#pragma unroll
  for (int p = 0; p < 4; p++) {
    int r = p * 16 + (t >> 4);
    int c4 = (t & 15) * 4;
    int4 q = *(const int4*)(inc + (long)(v0 + r) * NE + e0 + c4);
    ushort4 w;
    w.x = q.x > 0 ? 0x3F80 : 0;
    w.y = q.y > 0 ? 0x3F80 : 0;
    w.z = q.z > 0 ? 0x3F80 : 0;
    w.w = q.w > 0 ? 0x3F80 : 0;
    *(ushort4*)&Mbf[(long)(v0 + r) * NE + e0 + c4] = w;
    tile[c4 + 0][r] = w.x;
    tile[c4 + 1][r] = w.y;
    tile[c4 + 2][r] = w.z;
    tile[c4 + 3][r] = w.w;
  }
  __syncthreads();
#pragma unroll
  for (int p = 0; p < 4; p++) {
    int er = p * 16 + (t >> 4);
    int vc4 = (t & 15) * 4;
    ushort4 w;
    w.x = tile[er][vc4 + 0];
    w.y = tile[er][vc4 + 1];
    w.z = tile[er][vc4 + 2];
    w.w = tile[er][vc4 + 3];
    *(ushort4*)&Mtbf[(long)(e0 + er) * NV + v0 + vc4] = w;
  }
}

// Whht[c][u] = bf16(Wh[u][c]) — transpose to [256][1024] bf16
__global__ __launch_bounds__(256) void k_trw(const float* __restrict__ Wh,
                                             u16* __restrict__ Whht) {
  __shared__ u16 tile[64][65];
  const int c0 = blockIdx.x * 64, v0 = blockIdx.y * 64;
  const int t = threadIdx.x;
#pragma unroll
  for (int p = 0; p < 4; p++) {
    int r = p * 16 + (t >> 4);
    int c4 = (t & 15) * 4;
    float4 q = *(const float4*)(Wh + (long)(v0 + r) * 256 + c0 + c4);
    tile[c4 + 0][r] = f2bf(q.x);
    tile[c4 + 1][r] = f2bf(q.y);
    tile[c4 + 2][r] = f2bf(q.z);
    tile[c4 + 3][r] = f2bf(q.w);
  }
  __syncthreads();
#pragma unroll
  for (int p = 0; p < 4; p++) {
    int cr = p * 16 + (t >> 4);
    int vc4 = (t & 15) * 4;
    ushort4 w;
    w.x = tile[cr][vc4 + 0];
    w.y = tile[cr][vc4 + 1];
    w.z = tile[cr][vc4 + 2];
    w.w = tile[cr][vc4 + 3];
    *(ushort4*)&Whht[(long)(c0 + cr) * NV + v0 + vc4] = w;
  }
}

// qv[v,h] = Whh[v,h,:].a_v ; qe[v,h] = Whh[v,h,:].a_e
__global__ __launch_bounds__(256) void k_qse1(const float* __restrict__ Wh,
                                              const float* __restrict__ attn_w,
                                              float* __restrict__ qv, float* __restrict__ qe) {
  int v = blockIdx.x, t = threadIdx.x;
  int d = t & 63, h = t >> 6;
  float x = Wh[(long)v * 256 + t];
  float pv = x * attn_w[d];
  float pe = x * attn_w[64 + d];
  for (int s = 32; s; s >>= 1) {
    pv += __shfl_down(pv, s);
    pe += __shfl_down(pe, s);
  }
  if (d == 0) {
    qv[v * 4 + h] = pv;
    qe[v * 4 + h] = pe;
  }
}

// Partial cnt_e and se-sums over a 32-vertex slab.
__global__ __launch_bounds__(256) void k_cntse(const int* __restrict__ inc,
                                               const float* __restrict__ qe,
                                               float* __restrict__ part) {
  int e = blockIdx.x * 256 + threadIdx.x;
  int b = blockIdx.y;
  int v0 = b * 32;
  float c = 0, s0 = 0, s1 = 0, s2 = 0, s3 = 0;
  for (int v = v0; v < v0 + 32; v++) {
    if (inc[(long)v * NE + e] > 0) {
      c += 1.f;
      s0 += qe[v * 4 + 0];
      s1 += qe[v * 4 + 1];
      s2 += qe[v * 4 + 2];
      s3 += qe[v * 4 + 3];
    }
  }
  part[(0 * 32 + b) * NE + e] = c;
  part[(1 * 32 + b) * NE + e] = s0;
  part[(2 * 32 + b) * NE + e] = s1;
  part[(3 * 32 + b) * NE + e] = s2;
  part[(4 * 32 + b) * NE + e] = s3;
}

// Deterministic reduction of the 32 slabs. se holds RAW sums.
__global__ __launch_bounds__(256) void k_sered(const float* __restrict__ part,
                                               float* __restrict__ cnt, float* __restrict__ se) {
  int e = blockIdx.x * 256 + threadIdx.x;
  int j = blockIdx.y;
  float s = 0;
  for (int b = 0; b < 32; b++) s += part[(j * 32 + b) * NE + e];
  if (j == 0)
    cnt[e] = s;
  else
    se[e * 4 + (j - 1)] = s;
}

// Per (v,u): gate G via 2->32->1 MLP, and wce (bf16) = ce . (enc_w @ a_c)
__global__ __launch_bounds__(256) void k_G(const float* __restrict__ ce,
                                           const float* __restrict__ enc_w,
                                           const float* __restrict__ attn_w,
                                           const float* __restrict__ g1w,
                                           const float* __restrict__ g1b,
                                           const float* __restrict__ g2w,
                                           const float* __restrict__ g2b,
                                           float* __restrict__ G, u16* __restrict__ wce) {
  long idx = (long)blockIdx.x * 256 + threadIdx.x;
  float2 c = *(const float2*)(ce + idx * 2);
  float ew0 = 0, ew1 = 0;
#pragma unroll
  for (int j = 0; j < 8; j++) {
    float ac = attn_w[128 + j];
    ew0 += enc_w[j] * ac;
    ew1 += enc_w[8 + j] * ac;
  }
  wce[idx] = f2bf(c.x * ew0 + c.y * ew1);
  float s = g2b[0];
#pragma unroll
  for (int j = 0; j < 32; j++) {
    float zz = fmaxf(c.x * g1w[j] + c.y * g1w[32 + j] + g1b[j], 0.f);
    s = fmaf(zz, g2w[j], s);
  }
  G[idx] = 1.f / (1.f + expf(-s));
}

// Per v: scores -> leaky_relu -> mask -> softmax over E -> ap (bf16 planes), s_v
__global__ __launch_bounds__(256) void k_softmax(
    const float* __restrict__ P, const int* __restrict__ inc, const float* __restrict__ cnt,
    const float* __restrict__ qv, const float* __restrict__ se, const float* __restrict__ ce,
    const float* __restrict__ enc_w, const float* __restrict__ attn_w,
    const float* __restrict__ enc_b, u16* __restrict__ ap, float* __restrict__ sv) {
  int v = blockIdx.x, t = threadIdx.x;
  float ew0 = 0, ew1 = 0, ebac = 0;
#pragma unroll
  for (int j = 0; j < 8; j++) {
    float ac = attn_w[128 + j];
    ew0 += enc_w[j] * ac;
    ew1 += enc_w[8 + j] * ac;
    ebac += enc_b[j] * ac;
  }
  float dce = ce[((long)v * NV + v) * 2] * ew0 + ce[((long)v * NV + v) * 2 + 1] * ew1;
  float svh[4];
#pragma unroll
  for (int hh = 0; hh < 4; hh++) svh[hh] = qv[v * 4 + hh];

  float sc[8][4];
  float invn[8], msk[8];
  float mx[4] = {-3e38f, -3e38f, -3e38f, -3e38f};
  for (int i = 0; i < 8; i++) {
    int e = t + i * 256;
    float cnte = cnt[e];
    float mask = inc[(long)v * NE + e] > 0 ? 1.f : 0.f;
    float nve = cnte - mask;
    float inv = nve > 0.f ? 1.f / nve : 0.f;
    float rdg = 1.f / fmaxf(cnte, 1.f);
    invn[i] = inv;
    msk[i] = mask;
    float cc = inv * (P[(long)v * NE + e] - mask * dce) + ebac;
#pragma unroll
    for (int hh = 0; hh < 4; hh++) {
      float s = svh[hh] + se[e * 4 + hh] * rdg + cc;
      s = s > 0.f ? s : 0.2f * s;
      s = mask > 0.f ? s : -1e9f;
      sc[i][hh] = s;
      mx[hh] = fmaxf(mx[hh], s);
    }
  }
  __shared__ float red[4][256];
#pragma unroll
  for (int hh = 0; hh < 4; hh++) red[hh][t] = mx[hh];
  __syncthreads();
  for (int s = 128; s; s >>= 1) {
    if (t < s)
#pragma unroll
      for (int hh = 0; hh < 4; hh++) red[hh][t] = fmaxf(red[hh][t], red[hh][t + s]);
    __syncthreads();
  }
  float gm[4];
#pragma unroll
  for (int hh = 0; hh < 4; hh++) gm[hh] = red[hh][0];
  __syncthreads();

  float lsum[4] = {0, 0, 0, 0};
  for (int i = 0; i < 8; i++)
#pragma unroll
    for (int hh = 0; hh < 4; hh++) {
      float p = expf(sc[i][hh] - gm[hh]);
      sc[i][hh] = p;
      lsum[hh] += p;
    }
#pragma unroll
  for (int hh = 0; hh < 4; hh++) red[hh][t] = lsum[hh];
  __syncthreads();
  for (int s = 128; s; s >>= 1) {
    if (t < s)
#pragma unroll
      for (int hh = 0; hh < 4; hh++) red[hh][t] += red[hh][t + s];
    __syncthreads();
  }
  float inv_s[4];
#pragma unroll
  for (int hh = 0; hh < 4; hh++) inv_s[hh] = 1.f / red[hh][0];
  __syncthreads();

  float lsv[4] = {0, 0, 0, 0};
  for (int i = 0; i < 8; i++) {
    int e = t + i * 256;
#pragma unroll
    for (int hh = 0; hh < 4; hh++) {
      float a = sc[i][hh] * inv_s[hh] * msk[i] * invn[i];
      ap[(long)hh * NV * NE + (long)v * NE + e] = f2bf(a);
      lsv[hh] += a;
    }
  }
#pragma unroll
  for (int hh = 0; hh < 4; hh++) red[hh][t] = lsv[hh];
  __syncthreads();
  for (int s = 128; s; s >>= 1) {
    if (t < s)
#pragma unroll
      for (int hh = 0; hh < 4; hh++) red[hh][t] += red[hh][t + s];
    __syncthreads();
  }
  if (t == 0)
#pragma unroll
    for (int hh = 0; hh < 4; hh++) sv[v * 4 + hh] = red[hh][0];
}

// Fused: sum 8 split-K partials + residual + LayerNorm -> out
__global__ __launch_bounds__(256) void k_redln(
    const float* __restrict__ part, const float* __restrict__ Wh,
    const float* __restrict__ G, const float* __restrict__ sv,
    const float* __restrict__ lng, const float* __restrict__ lnb,
    float* __restrict__ out) {
  int v = blockIdx.x, t = threadIdx.x;
  float x = 0.f;
#pragma unroll
  for (int s = 0; s < 8; s++) x += part[(long)s * NV * 256 + (long)v * 256 + t];
  int z = t >> 6;
  float corr = 1.f - sv[v * 4 + z] * G[(long)v * NV + v];
  x += Wh[(long)v * 256 + t] * corr;
  __shared__ float red[256];
  red[t] = x;
  __syncthreads();
  for (int s = 128; s; s >>= 1) {
    if (t < s) red[t] += red[t + s];
    __syncthreads();
  }
  float mu = red[0] * (1.f / 256.f);
  __syncthreads();
  float d = x - mu;
  red[t] = d * d;
  __syncthreads();
  for (int s = 128; s; s >>= 1) {
    if (t < s) red[t] += red[t + s];
    __syncthreads();
  }
  float var = red[0] * (1.f / 256.f);
  out[(long)v * 256 + t] = d / sqrtf(var + 1e-5f) * lng[t] + lnb[t];
}

extern "C" void kernel_launch(void* const* d_in, const int* in_sizes, int n_in,
                              void* d_out, int out_size, void* d_ws, size_t ws_size,
                              hipStream_t stream) {
  const float* h = (const float*)d_in[0];
  const float* ce = (const float*)d_in[1];
  const float* W = (const float*)d_in[2];
  const float* attn_w = (const float*)d_in[3];
  const float* enc_w = (const float*)d_in[4];
  const float* enc_b = (const float*)d_in[5];
  const float* g1w = (const float*)d_in[6];
  const float* g1b = (const float*)d_in[7];
  const float* g2w = (const float*)d_in[8];
  const float* g2b = (const float*)d_in[9];
  const float* lng = (const float*)d_in[10];
  const float* lnb = (const float*)d_in[11];
  const int* inc = (const int*)d_in[12];
  float* out = (float*)d_out;

  size_t off = 0;
  char* base = (char*)d_ws;
  auto alloc = [&](size_t bytes) {
    void* p = base + off;
    off += (bytes + 255) & ~(size_t)255;
    return p;
  };
  float* Wh = (float*)alloc((size_t)NV * 256 * 4);
  float* cnt = (float*)alloc((size_t)NE * 4);
  float* qv = (float*)alloc((size_t)NV * 4 * 4);
  float* qe = (float*)alloc((size_t)NV * 4 * 4);
  float* se = (float*)alloc((size_t)NE * 4 * 4);
  float* sv = (float*)alloc((size_t)NV * 4 * 4);
  float* G = (float*)alloc((size_t)NV * NV * 4);
  u16* wce = (u16*)alloc((size_t)NV * NV * 2);
  u16* Mbf = (u16*)alloc((size_t)NV * NE * 2);
  u16* Whht = (u16*)alloc((size_t)256 * NV * 2);
  float* P = (float*)alloc((size_t)NV * NE * 4);  // also: split-K partials (8MB)
  u16* ap = (u16*)alloc((size_t)4 * NV * NE * 2);
  u16* Bh = (u16*)alloc((size_t)4 * NV * NV * 2);
  // aliases (lifetimes don't overlap):
  float* part = P;    // cnt/se partials (1.25MB), dead before P written
  u16* Mtbf = Bh;     // Mtbf (4MB) dead before Bh written
  float* part8 = P;   // step-8 split-K partials, P dead after k_softmax
  (void)ws_size;
  (void)in_sizes;
  (void)n_in;
  (void)out_size;

  // 0. bf16 incidence (row-major + transposed)
  k_conv<<<dim3(NE / 64, NV / 64), 256, 0, stream>>>(inc, Mbf, Mtbf);
  // 1. Wh = h @ W (f32)
  mm_f32<<<dim3(256 / 64, NV / 64), 256, 0, stream>>>(h, W, Wh);
  // 1b. Whht = Wh^T bf16
  k_trw<<<dim3(256 / 64, NV / 64), 256, 0, stream>>>(Wh, Whht);
  // 2. qv, qe
  k_qse1<<<NV, 256, 0, stream>>>(Wh, attn_w, qv, qe);
  // 3. cnt_e + se sums
  k_cntse<<<dim3(NE / 256, 32), 256, 0, stream>>>(inc, qe, part);
  k_sered<<<dim3(NE / 256, 5), 256, 0, stream>>>(part, cnt, se);
  // 4. G, wce(bf16)
  k_G<<<(NV * NV) / 256, 256, 0, stream>>>(ce, enc_w, attn_w, g1w, g1b, g2w, g2b, G, wce);
  // 5. P = wce @ M (M=1024, N=2048, K=1024), BT = Mtbf. 64x64 tiles -> 512 blocks.
  mfma_bt<64, 64, 0><<<dim3(NE / 64, NV / 64, 1), 256, 0, stream>>>(
      wce, NV, 0, Mtbf, NV, 0, P, NE, 0, NV, nullptr);
  // 6. softmax -> ap planes (bf16), s_v
  k_softmax<<<NV, 256, 0, stream>>>(P, inc, cnt, qv, se, ce, enc_w, attn_w, enc_b, ap, sv);
  // 7. Bh = (ap_h @ M^T) * G (4 x M=N=1024, K=2048). 128x64 tiles -> 512 blocks.
  mfma_bt<128, 64, 1><<<dim3(NV / 64, NV / 128, 4), 256, 0, stream>>>(
      ap, NE, (long)NV * NE, Mbf, NE, 0, Bh, NV, (long)NV * NV, NE, G);
  // 8. split-K=8 partials: part8[s][m][z*64+n] = Bh_z[m, ks] @ Whh_z[ks, n]
  mfma_bt<128, 64, 2><<<dim3(1, NV / 128, 32), 256, 0, stream>>>(
      Bh, NV, (long)NV * NV, Whht, NV, (long)64 * NV, part8, 256, 0, 128, nullptr);
  // 9. reduce partials + residual + LayerNorm
  k_redln<<<NV, 256, 0, stream>>>(part8, Wh, G, sv, lng, lnb, out);
}

// Round 6
// 129.094 us; speedup vs baseline: 4.7572x; 1.0491x over previous
//
#include <hip/hip_runtime.h>
#include <hip/hip_bf16.h>

#define NV 1024
#define NE 2048

typedef unsigned short u16;
typedef __attribute__((ext_vector_type(8))) short bf16x8;
typedef __attribute__((ext_vector_type(4))) float f32x4;

__device__ __forceinline__ float bf2f(u16 u) { return __uint_as_float(((unsigned)u) << 16); }
__device__ __forceinline__ u16 f2bf(float f) {
  unsigned x = __float_as_uint(f);
  return (u16)((x + 0x7fffu + ((x >> 16) & 1u)) >> 16);
}

// async global->LDS, 16B per lane, wave-uniform LDS base + lane*16
#define GLL(src, dst)                                                        \
  __builtin_amdgcn_global_load_lds(                                          \
      (const __attribute__((address_space(1))) void*)(src),                  \
      (__attribute__((address_space(3))) void*)(dst), 16, 0, 0)

// Swizzled LDS layout: logical byte L lives at physical P = L ^ (((L>>6)&7)<<4)
// (bijective). global_load_lds writes linear physical granules, so the
// per-lane GLOBAL SOURCE is permuted by the inverse map; reads apply fwdswz.
__device__ __forceinline__ void invswz(int g, int& row, int& kq) {
  int pb = g * 16;
  int lb = pb ^ ((((pb >> 8) & 1) << 6) | (((pb >> 7) & 1) << 5) |
                 ((((pb >> 6) ^ (pb >> 8)) & 1) << 4));
  row = lb >> 6;
  kq = lb & 63;
}
__device__ __forceinline__ int fwdswz(int la) { return la ^ (((la >> 6) & 7) << 4); }

// ---------------------------------------------------------------------------
// bt-GEMM, 2-phase double-buffered (T3 minimum form): C(M,N) = A @ BT^T,
// A row-major [M][K] bf16, BT row-major [N][K] bf16. Tile BM x BN, BK=32,
// 4 waves (2x2), wave-tile (BM/2)x(BN/2), 16x16x32 frags. Staging via
// global_load_lds(16). Next tile's STAGE is issued BEFORE computing the
// current tile; the __syncthreads() at phase end provides the single
// vmcnt(0)+barrier per tile. Statically distinct LDS buffers (As0/As1) so
// alias analysis doesn't serialize ds_read against in-flight GLL.
// EPI 0: f32 store. EPI 1: bf16 store of acc * Gm[m][n].
// EPI 2: split-K f32 partial (blockIdx.z = z*8+ks, K=128 slice).
// Requires K/32 even.
// ---------------------------------------------------------------------------
template <int BM, int BN, int EPI>
__global__ __launch_bounds__(256) void mfma_bt(
    const u16* __restrict__ A, int lda, long sA,
    const u16* __restrict__ BT, int ldb, long sBT,
    void* __restrict__ Cp, int ldc, long sC, int K,
    const float* __restrict__ Gm) {
  constexpr int FM = BM / 32, FN = BN / 32;
  __shared__ __align__(16) char As0[BM * 64];
  __shared__ __align__(16) char As1[BM * 64];
  __shared__ __align__(16) char Bs0[BN * 64];
  __shared__ __align__(16) char Bs1[BN * 64];
  const int t = threadIdx.x;
  const int wave = t >> 6, lane = t & 63;
  const int lhi = lane >> 4, llo = lane & 15;
  const int wm = (wave >> 1) * (BM / 2), wn = (wave & 1) * (BN / 2);
  const int m0 = blockIdx.y * BM, n0 = blockIdx.x * BN;
  int zz = blockIdx.z, ks = 0;
  const char* Ab;
  const char* Bb;
  if constexpr (EPI == 2) {
    zz = blockIdx.z >> 3;
    ks = blockIdx.z & 7;
    Ab = (const char*)(A + sA * zz + ks * 128);
    Bb = (const char*)(BT + sBT * zz + ks * 128);
  } else {
    Ab = (const char*)(A + sA * zz);
    Bb = (const char*)(BT + sBT * zz);
  }
  const long lda2 = (long)lda * 2, ldb2 = (long)ldb * 2;

  int rA0, qA0, rA1, qA1;
  invswz(t, rA0, qA0);
  invswz(t + 256, rA1, qA1);
  const int wofs = (t & 192) * 16;

  f32x4 acc[FM][FN] = {};

  auto stage = [&](char* Ad, char* Bd, int k0) {
    const long kb = (long)k0 * 2;
    GLL(Ab + (long)(m0 + rA0) * lda2 + kb + qA0, Ad + wofs);
    if constexpr (BM == 128) GLL(Ab + (long)(m0 + rA1) * lda2 + kb + qA1, Ad + 4096 + wofs);
    GLL(Bb + (long)(n0 + rA0) * ldb2 + kb + qA0, Bd + wofs);
    if constexpr (BN == 128) GLL(Bb + (long)(n0 + rA1) * ldb2 + kb + qA1, Bd + 4096 + wofs);
  };
  auto compute = [&](const char* A_, const char* B_) {
    bf16x8 af[FM], bfv[FN];
#pragma unroll
    for (int mi = 0; mi < FM; mi++) {
      int la = (wm + mi * 16 + llo) * 64 + lhi * 16;
      af[mi] = *(const bf16x8*)(A_ + fwdswz(la));
    }
#pragma unroll
    for (int ni = 0; ni < FN; ni++) {
      int la = (wn + ni * 16 + llo) * 64 + lhi * 16;
      bfv[ni] = *(const bf16x8*)(B_ + fwdswz(la));
    }
#pragma unroll
    for (int mi = 0; mi < FM; mi++)
#pragma unroll
      for (int ni = 0; ni < FN; ni++)
        acc[mi][ni] =
            __builtin_amdgcn_mfma_f32_16x16x32_bf16(af[mi], bfv[ni], acc[mi][ni], 0, 0, 0);
  };

  const int nt = K / 32;  // even for all call sites
  stage(As0, Bs0, 0);
  __syncthreads();
  for (int i = 0; i < nt / 2 - 1; i++) {
    stage(As1, Bs1, (2 * i + 1) * 32);
    compute(As0, Bs0);
    __syncthreads();
    stage(As0, Bs0, (2 * i + 2) * 32);
    compute(As1, Bs1);
    __syncthreads();
  }
  stage(As1, Bs1, (nt - 1) * 32);
  compute(As0, Bs0);
  __syncthreads();
  compute(As1, Bs1);

#pragma unroll
  for (int mi = 0; mi < FM; mi++)
#pragma unroll
    for (int ni = 0; ni < FN; ni++)
#pragma unroll
      for (int r = 0; r < 4; r++) {
        int m = m0 + wm + mi * 16 + lhi * 4 + r;
        int n = n0 + wn + ni * 16 + llo;
        float vv = acc[mi][ni][r];
        if constexpr (EPI == 0) {
          ((float*)Cp)[sC * zz + (long)m * ldc + n] = vv;
        } else if constexpr (EPI == 1) {
          ((u16*)Cp)[sC * zz + (long)m * ldc + n] = f2bf(vv * Gm[(long)m * NV + n]);
        } else {
          ((float*)Cp)[(long)ks * (NV * 256) + (long)m * 256 + zz * 64 + n] = vv;
        }
      }
}

// ---------------------------------------------------------------------------
// f32 tiled matmul for step 1 only (Wh = h @ W). 64x64 tile, BK=16.
// ---------------------------------------------------------------------------
__global__ __launch_bounds__(256) void mm_f32(
    const float* __restrict__ Ap, const float* __restrict__ Bp,
    float* __restrict__ Cp) {
  __shared__ float As[16][68];
  __shared__ float Bs[16][68];
  const int t = threadIdx.x;
  const int tx = t & 15, ty = t >> 4;
  const int m0 = blockIdx.y * 64, n0 = blockIdx.x * 64;
  const int lr = t >> 2, lc4 = (t & 3) * 4;
  const int bk = t >> 4, bn = (t & 15) * 4;
  float acc[4][4] = {};
  for (int k0 = 0; k0 < 256; k0 += 16) {
    float4 a4 = *(const float4*)(Ap + (long)(m0 + lr) * 256 + k0 + lc4);
    As[lc4 + 0][lr] = a4.x;
    As[lc4 + 1][lr] = a4.y;
    As[lc4 + 2][lr] = a4.z;
    As[lc4 + 3][lr] = a4.w;
    float4 b4 = *(const float4*)(Bp + (long)(k0 + bk) * 256 + n0 + bn);
    Bs[bk][bn + 0] = b4.x;
    Bs[bk][bn + 1] = b4.y;
    Bs[bk][bn + 2] = b4.z;
    Bs[bk][bn + 3] = b4.w;
    __syncthreads();
#pragma unroll
    for (int kk = 0; kk < 16; kk++) {
      float a[4], b[4];
      *(float4*)a = *(const float4*)&As[kk][ty * 4];
      *(float4*)b = *(const float4*)&Bs[kk][tx * 4];
#pragma unroll
      for (int i = 0; i < 4; i++)
#pragma unroll
        for (int j = 0; j < 4; j++) acc[i][j] = fmaf(a[i], b[j], acc[i][j]);
    }
    __syncthreads();
  }
#pragma unroll
  for (int i = 0; i < 4; i++)
#pragma unroll
    for (int j = 0; j < 4; j++)
      Cp[(long)(m0 + ty * 4 + i) * 256 + n0 + tx * 4 + j] = acc[i][j];
}

// Build Mbf[v][e] (bf16 1/0) and Mtbf[e][v] via LDS-tiled transpose.
__global__ __launch_bounds__(256) void k_conv(const int* __restrict__ inc,
                                              u16* __restrict__ Mbf,
                                              u16* __restrict__ Mtbf) {
  __shared__ u16 tile[64][65];
  const int e0 = blockIdx.x * 64, v0 = blockIdx.y * 64;
  const int t = threadIdx.x;
#pragma unroll
  for (int p = 0; p < 4; p++) {
    int r = p * 16 + (t >> 4);
    int c4 = (t & 15) * 4;
    int4 q = *(const int4*)(inc + (long)(v0 + r) * NE + e0 + c4);
    ushort4 w;
    w.x = q.x > 0 ? 0x3F80 : 0;
    w.y = q.y > 0 ? 0x3F80 : 0;
    w.z = q.z > 0 ? 0x3F80 : 0;
    w.w = q.w > 0 ? 0x3F80 : 0;
    *(ushort4*)&Mbf[(long)(v0 + r) * NE + e0 + c4] = w;
    tile[c4 + 0][r] = w.x;
    tile[c4 + 1][r] = w.y;
    tile[c4 + 2][r] = w.z;
    tile[c4 + 3][r] = w.w;
  }
  __syncthreads();
#pragma unroll
  for (int p = 0; p < 4; p++) {
    int er = p * 16 + (t >> 4);
    int vc4 = (t & 15) * 4;
    ushort4 w;
    w.x = tile[er][vc4 + 0];
    w.y = tile[er][vc4 + 1];
    w.z = tile[er][vc4 + 2];
    w.w = tile[er][vc4 + 3];
    *(ushort4*)&Mtbf[(long)(e0 + er) * NV + v0 + vc4] = w;
  }
}

// Whht[c][u] = bf16(Wh[u][c]) — transpose to [256][1024] bf16
__global__ __launch_bounds__(256) void k_trw(const float* __restrict__ Wh,
                                             u16* __restrict__ Whht) {
  __shared__ u16 tile[64][65];
  const int c0 = blockIdx.x * 64, v0 = blockIdx.y * 64;
  const int t = threadIdx.x;
#pragma unroll
  for (int p = 0; p < 4; p++) {
    int r = p * 16 + (t >> 4);
    int c4 = (t & 15) * 4;
    float4 q = *(const float4*)(Wh + (long)(v0 + r) * 256 + c0 + c4);
    tile[c4 + 0][r] = f2bf(q.x);
    tile[c4 + 1][r] = f2bf(q.y);
    tile[c4 + 2][r] = f2bf(q.z);
    tile[c4 + 3][r] = f2bf(q.w);
  }
  __syncthreads();
#pragma unroll
  for (int p = 0; p < 4; p++) {
    int cr = p * 16 + (t >> 4);
    int vc4 = (t & 15) * 4;
    ushort4 w;
    w.x = tile[cr][vc4 + 0];
    w.y = tile[cr][vc4 + 1];
    w.z = tile[cr][vc4 + 2];
    w.w = tile[cr][vc4 + 3];
    *(ushort4*)&Whht[(long)(c0 + cr) * NV + v0 + vc4] = w;
  }
}

// qv[v,h] = Whh[v,h,:].a_v ; qe[v,h] = Whh[v,h,:].a_e
__global__ __launch_bounds__(256) void k_qse1(const float* __restrict__ Wh,
                                              const float* __restrict__ attn_w,
                                              float* __restrict__ qv, float* __restrict__ qe) {
  int v = blockIdx.x, t = threadIdx.x;
  int d = t & 63, h = t >> 6;
  float x = Wh[(long)v * 256 + t];
  float pv = x * attn_w[d];
  float pe = x * attn_w[64 + d];
  for (int s = 32; s; s >>= 1) {
    pv += __shfl_down(pv, s);
    pe += __shfl_down(pe, s);
  }
  if (d == 0) {
    qv[v * 4 + h] = pv;
    qe[v * 4 + h] = pe;
  }
}

// Partial cnt_e and se-sums over a 32-vertex slab.
__global__ __launch_bounds__(256) void k_cntse(const int* __restrict__ inc,
                                               const float* __restrict__ qe,
                                               float* __restrict__ part) {
  int e = blockIdx.x * 256 + threadIdx.x;
  int b = blockIdx.y;
  int v0 = b * 32;
  float c = 0, s0 = 0, s1 = 0, s2 = 0, s3 = 0;
  for (int v = v0; v < v0 + 32; v++) {
    if (inc[(long)v * NE + e] > 0) {
      c += 1.f;
      s0 += qe[v * 4 + 0];
      s1 += qe[v * 4 + 1];
      s2 += qe[v * 4 + 2];
      s3 += qe[v * 4 + 3];
    }
  }
  part[(0 * 32 + b) * NE + e] = c;
  part[(1 * 32 + b) * NE + e] = s0;
  part[(2 * 32 + b) * NE + e] = s1;
  part[(3 * 32 + b) * NE + e] = s2;
  part[(4 * 32 + b) * NE + e] = s3;
}

// Deterministic reduction of the 32 slabs. se holds RAW sums.
__global__ __launch_bounds__(256) void k_sered(const float* __restrict__ part,
                                               float* __restrict__ cnt, float* __restrict__ se) {
  int e = blockIdx.x * 256 + threadIdx.x;
  int j = blockIdx.y;
  float s = 0;
  for (int b = 0; b < 32; b++) s += part[(j * 32 + b) * NE + e];
  if (j == 0)
    cnt[e] = s;
  else
    se[e * 4 + (j - 1)] = s;
}

// Per (v,u): gate G via 2->32->1 MLP, and wce (bf16) = ce . (enc_w @ a_c)
__global__ __launch_bounds__(256) void k_G(const float* __restrict__ ce,
                                           const float* __restrict__ enc_w,
                                           const float* __restrict__ attn_w,
                                           const float* __restrict__ g1w,
                                           const float* __restrict__ g1b,
                                           const float* __restrict__ g2w,
                                           const float* __restrict__ g2b,
                                           float* __restrict__ G, u16* __restrict__ wce) {
  long idx = (long)blockIdx.x * 256 + threadIdx.x;
  float2 c = *(const float2*)(ce + idx * 2);
  float ew0 = 0, ew1 = 0;
#pragma unroll
  for (int j = 0; j < 8; j++) {
    float ac = attn_w[128 + j];
    ew0 += enc_w[j] * ac;
    ew1 += enc_w[8 + j] * ac;
  }
  wce[idx] = f2bf(c.x * ew0 + c.y * ew1);
  float s = g2b[0];
#pragma unroll
  for (int j = 0; j < 32; j++) {
    float zz = fmaxf(c.x * g1w[j] + c.y * g1w[32 + j] + g1b[j], 0.f);
    s = fmaf(zz, g2w[j], s);
  }
  G[idx] = 1.f / (1.f + expf(-s));
}

// Per v: scores -> leaky_relu -> mask -> softmax over E -> ap (bf16 planes), s_v
__global__ __launch_bounds__(256) void k_softmax(
    const float* __restrict__ P, const int* __restrict__ inc, const float* __restrict__ cnt,
    const float* __restrict__ qv, const float* __restrict__ se, const float* __restrict__ ce,
    const float* __restrict__ enc_w, const float* __restrict__ attn_w,
    const float* __restrict__ enc_b, u16* __restrict__ ap, float* __restrict__ sv) {
  int v = blockIdx.x, t = threadIdx.x;
  float ew0 = 0, ew1 = 0, ebac = 0;
#pragma unroll
  for (int j = 0; j < 8; j++) {
    float ac = attn_w[128 + j];
    ew0 += enc_w[j] * ac;
    ew1 += enc_w[8 + j] * ac;
    ebac += enc_b[j] * ac;
  }
  float dce = ce[((long)v * NV + v) * 2] * ew0 + ce[((long)v * NV + v) * 2 + 1] * ew1;
  float svh[4];
#pragma unroll
  for (int hh = 0; hh < 4; hh++) svh[hh] = qv[v * 4 + hh];

  float sc[8][4];
  float invn[8], msk[8];
  float mx[4] = {-3e38f, -3e38f, -3e38f, -3e38f};
  for (int i = 0; i < 8; i++) {
    int e = t + i * 256;
    float cnte = cnt[e];
    float mask = inc[(long)v * NE + e] > 0 ? 1.f : 0.f;
    float nve = cnte - mask;
    float inv = nve > 0.f ? 1.f / nve : 0.f;
    float rdg = 1.f / fmaxf(cnte, 1.f);
    invn[i] = inv;
    msk[i] = mask;
    float cc = inv * (P[(long)v * NE + e] - mask * dce) + ebac;
#pragma unroll
    for (int hh = 0; hh < 4; hh++) {
      float s = svh[hh] + se[e * 4 + hh] * rdg + cc;
      s = s > 0.f ? s : 0.2f * s;
      s = mask > 0.f ? s : -1e9f;
      sc[i][hh] = s;
      mx[hh] = fmaxf(mx[hh], s);
    }
  }
  __shared__ float red[4][256];
#pragma unroll
  for (int hh = 0; hh < 4; hh++) red[hh][t] = mx[hh];
  __syncthreads();
  for (int s = 128; s; s >>= 1) {
    if (t < s)
#pragma unroll
      for (int hh = 0; hh < 4; hh++) red[hh][t] = fmaxf(red[hh][t], red[hh][t + s]);
    __syncthreads();
  }
  float gm[4];
#pragma unroll
  for (int hh = 0; hh < 4; hh++) gm[hh] = red[hh][0];
  __syncthreads();

  float lsum[4] = {0, 0, 0, 0};
  for (int i = 0; i < 8; i++)
#pragma unroll
    for (int hh = 0; hh < 4; hh++) {
      float p = expf(sc[i][hh] - gm[hh]);
      sc[i][hh] = p;
      lsum[hh] += p;
    }
#pragma unroll
  for (int hh = 0; hh < 4; hh++) red[hh][t] = lsum[hh];
  __syncthreads();
  for (int s = 128; s; s >>= 1) {
    if (t < s)
#pragma unroll
      for (int hh = 0; hh < 4; hh++) red[hh][t] += red[hh][t + s];
    __syncthreads();
  }
  float inv_s[4];
#pragma unroll
  for (int hh = 0; hh < 4; hh++) inv_s[hh] = 1.f / red[hh][0];
  __syncthreads();

  float lsv[4] = {0, 0, 0, 0};
  for (int i = 0; i < 8; i++) {
    int e = t + i * 256;
#pragma unroll
    for (int hh = 0; hh < 4; hh++) {
      float a = sc[i][hh] * inv_s[hh] * msk[i] * invn[i];
      ap[(long)hh * NV * NE + (long)v * NE + e] = f2bf(a);
      lsv[hh] += a;
    }
  }
#pragma unroll
  for (int hh = 0; hh < 4; hh++) red[hh][t] = lsv[hh];
  __syncthreads();
  for (int s = 128; s; s >>= 1) {
    if (t < s)
#pragma unroll
      for (int hh = 0; hh < 4; hh++) red[hh][t] += red[hh][t + s];
    __syncthreads();
  }
  if (t == 0)
#pragma unroll
    for (int hh = 0; hh < 4; hh++) sv[v * 4 + hh] = red[hh][0];
}

// Fused: sum 8 split-K partials + residual + LayerNorm -> out
__global__ __launch_bounds__(256) void k_redln(
    const float* __restrict__ part, const float* __restrict__ Wh,
    const float* __restrict__ G, const float* __restrict__ sv,
    const float* __restrict__ lng, const float* __restrict__ lnb,
    float* __restrict__ out) {
  int v = blockIdx.x, t = threadIdx.x;
  float x = 0.f;
#pragma unroll
  for (int s = 0; s < 8; s++) x += part[(long)s * NV * 256 + (long)v * 256 + t];
  int z = t >> 6;
  float corr = 1.f - sv[v * 4 + z] * G[(long)v * NV + v];
  x += Wh[(long)v * 256 + t] * corr;
  __shared__ float red[256];
  red[t] = x;
  __syncthreads();
  for (int s = 128; s; s >>= 1) {
    if (t < s) red[t] += red[t + s];
    __syncthreads();
  }
  float mu = red[0] * (1.f / 256.f);
  __syncthreads();
  float d = x - mu;
  red[t] = d * d;
  __syncthreads();
  for (int s = 128; s; s >>= 1) {
    if (t < s) red[t] += red[t + s];
    __syncthreads();
  }
  float var = red[0] * (1.f / 256.f);
  out[(long)v * 256 + t] = d / sqrtf(var + 1e-5f) * lng[t] + lnb[t];
}

extern "C" void kernel_launch(void* const* d_in, const int* in_sizes, int n_in,
                              void* d_out, int out_size, void* d_ws, size_t ws_size,
                              hipStream_t stream) {
  const float* h = (const float*)d_in[0];
  const float* ce = (const float*)d_in[1];
  const float* W = (const float*)d_in[2];
  const float* attn_w = (const float*)d_in[3];
  const float* enc_w = (const float*)d_in[4];
  const float* enc_b = (const float*)d_in[5];
  const float* g1w = (const float*)d_in[6];
  const float* g1b = (const float*)d_in[7];
  const float* g2w = (const float*)d_in[8];
  const float* g2b = (const float*)d_in[9];
  const float* lng = (const float*)d_in[10];
  const float* lnb = (const float*)d_in[11];
  const int* inc = (const int*)d_in[12];
  float* out = (float*)d_out;

  size_t off = 0;
  char* base = (char*)d_ws;
  auto alloc = [&](size_t bytes) {
    void* p = base + off;
    off += (bytes + 255) & ~(size_t)255;
    return p;
  };
  float* Wh = (float*)alloc((size_t)NV * 256 * 4);
  float* cnt = (float*)alloc((size_t)NE * 4);
  float* qv = (float*)alloc((size_t)NV * 4 * 4);
  float* qe = (float*)alloc((size_t)NV * 4 * 4);
  float* se = (float*)alloc((size_t)NE * 4 * 4);
  float* sv = (float*)alloc((size_t)NV * 4 * 4);
  float* G = (float*)alloc((size_t)NV * NV * 4);
  u16* wce = (u16*)alloc((size_t)NV * NV * 2);
  u16* Mbf = (u16*)alloc((size_t)NV * NE * 2);
  u16* Whht = (u16*)alloc((size_t)256 * NV * 2);
  float* P = (float*)alloc((size_t)NV * NE * 4);  // also: split-K partials (8MB)
  u16* ap = (u16*)alloc((size_t)4 * NV * NE * 2);
  u16* Bh = (u16*)alloc((size_t)4 * NV * NV * 2);
  // aliases (lifetimes don't overlap):
  float* part = P;    // cnt/se partials (1.25MB), dead before P written
  u16* Mtbf = Bh;     // Mtbf (4MB) dead before Bh written
  float* part8 = P;   // step-8 split-K partials, P dead after k_softmax
  (void)ws_size;
  (void)in_sizes;
  (void)n_in;
  (void)out_size;

  // 0. bf16 incidence (row-major + transposed)
  k_conv<<<dim3(NE / 64, NV / 64), 256, 0, stream>>>(inc, Mbf, Mtbf);
  // 1. Wh = h @ W (f32)
  mm_f32<<<dim3(256 / 64, NV / 64), 256, 0, stream>>>(h, W, Wh);
  // 1b. Whht = Wh^T bf16
  k_trw<<<dim3(256 / 64, NV / 64), 256, 0, stream>>>(Wh, Whht);
  // 2. qv, qe
  k_qse1<<<NV, 256, 0, stream>>>(Wh, attn_w, qv, qe);
  // 3. cnt_e + se sums
  k_cntse<<<dim3(NE / 256, 32), 256, 0, stream>>>(inc, qe, part);
  k_sered<<<dim3(NE / 256, 5), 256, 0, stream>>>(part, cnt, se);
  // 4. G, wce(bf16)
  k_G<<<(NV * NV) / 256, 256, 0, stream>>>(ce, enc_w, attn_w, g1w, g1b, g2w, g2b, G, wce);
  // 5. P = wce @ M (M=1024, N=2048, K=1024), BT = Mtbf. 64x64 tiles -> 512 blocks.
  mfma_bt<64, 64, 0><<<dim3(NE / 64, NV / 64, 1), 256, 0, stream>>>(
      wce, NV, 0, Mtbf, NV, 0, P, NE, 0, NV, nullptr);
  // 6. softmax -> ap planes (bf16), s_v
  k_softmax<<<NV, 256, 0, stream>>>(P, inc, cnt, qv, se, ce, enc_w, attn_w, enc_b, ap, sv);
  // 7. Bh = (ap_h @ M^T) * G (4 x M=N=1024, K=2048). 128x64 tiles -> 512 blocks.
  mfma_bt<128, 64, 1><<<dim3(NV / 64, NV / 128, 4), 256, 0, stream>>>(
      ap, NE, (long)NV * NE, Mbf, NE, 0, Bh, NV, (long)NV * NV, NE, G);
  // 8. split-K=8 partials: part8[s][m][z*64+n] = Bh_z[m, ks] @ Whh_z[ks, n]
  mfma_bt<128, 64, 2><<<dim3(1, NV / 128, 32), 256, 0, stream>>>(
      Bh, NV, (long)NV * NV, Whht, NV, (long)64 * NV, part8, 256, 0, 128, nullptr);
  // 9. reduce partials + residual + LayerNorm
  k_redln<<<NV, 256, 0, stream>>>(part8, Wh, G, sv, lng, lnb, out);
}

// Round 7
// 122.736 us; speedup vs baseline: 5.0037x; 1.0518x over previous
//
#include <hip/hip_runtime.h>
#include <hip/hip_bf16.h>

#define NV 1024
#define NE 2048

typedef unsigned short u16;
typedef __attribute__((ext_vector_type(8))) short bf16x8;
typedef __attribute__((ext_vector_type(4))) float f32x4;

__device__ __forceinline__ float bf2f(u16 u) { return __uint_as_float(((unsigned)u) << 16); }
__device__ __forceinline__ u16 f2bf(float f) {
  unsigned x = __float_as_uint(f);
  return (u16)((x + 0x7fffu + ((x >> 16) & 1u)) >> 16);
}

// async global->LDS, 16B per lane, wave-uniform LDS base + lane*16
#define GLL(src, dst)                                                        \
  __builtin_amdgcn_global_load_lds(                                          \
      (const __attribute__((address_space(1))) void*)(src),                  \
      (__attribute__((address_space(3))) void*)(dst), 16, 0, 0)

// Counted vmcnt wait (T4): literal must be in the asm string.
template <int N>
__device__ __forceinline__ void waitcnt_vm() {
  if constexpr (N == 0) asm volatile("s_waitcnt vmcnt(0)" ::: "memory");
  else if constexpr (N == 1) asm volatile("s_waitcnt vmcnt(1)" ::: "memory");
  else if constexpr (N == 2) asm volatile("s_waitcnt vmcnt(2)" ::: "memory");
  else if constexpr (N == 3) asm volatile("s_waitcnt vmcnt(3)" ::: "memory");
  else if constexpr (N == 4) asm volatile("s_waitcnt vmcnt(4)" ::: "memory");
}
__device__ __forceinline__ void barrier_raw() { __builtin_amdgcn_s_barrier(); }

// Swizzled LDS layout: logical byte L lives at physical P = L ^ (((L>>6)&7)<<4)
// (bijective). global_load_lds writes linear physical granules, so the
// per-lane GLOBAL SOURCE is permuted by the inverse map; reads apply fwdswz.
__device__ __forceinline__ void invswz(int g, int& row, int& kq) {
  int pb = g * 16;
  int lb = pb ^ ((((pb >> 8) & 1) << 6) | (((pb >> 7) & 1) << 5) |
                 ((((pb >> 6) ^ (pb >> 8)) & 1) << 4));
  row = lb >> 6;
  kq = lb & 63;
}
__device__ __forceinline__ int fwdswz(int la) { return la ^ (((la >> 6) & 7) << 4); }

// ---------------------------------------------------------------------------
// bt-GEMM, 2-phase double-buffered with COUNTED vmcnt (T3+T4 minimum form):
// C(M,N) = A @ BT^T, A row-major [M][K] bf16, BT row-major [N][K] bf16.
// Tile BM x BN, BK=32, 4 waves (2x2), 16x16x32 frags. Per tile:
//   stage(next) ; s_waitcnt vmcnt(S) ; s_barrier ; compute(cur) ; s_barrier
// Next-tile loads stay in flight across the whole compute phase — never
// drained to 0 in the main loop (the m97-structure stall).
// EPI 0: f32 store. EPI 1: bf16 store of acc * Gm[m][n].
// EPI 2: split-K f32 partial (blockIdx.z = z*8+ks, K=128 slice).
// Requires K/32 even.
// ---------------------------------------------------------------------------
template <int BM, int BN, int EPI>
__global__ __launch_bounds__(256) void mfma_bt(
    const u16* __restrict__ A, int lda, long sA,
    const u16* __restrict__ BT, int ldb, long sBT,
    void* __restrict__ Cp, int ldc, long sC, int K,
    const float* __restrict__ Gm) {
  constexpr int FM = BM / 32, FN = BN / 32;
  constexpr int S = (BM == 128 ? 2 : 1) + (BN == 128 ? 2 : 1);  // GLLs per stage
  __shared__ __align__(16) char As0[BM * 64];
  __shared__ __align__(16) char As1[BM * 64];
  __shared__ __align__(16) char Bs0[BN * 64];
  __shared__ __align__(16) char Bs1[BN * 64];
  const int t = threadIdx.x;
  const int wave = t >> 6, lane = t & 63;
  const int lhi = lane >> 4, llo = lane & 15;
  const int wm = (wave >> 1) * (BM / 2), wn = (wave & 1) * (BN / 2);
  const int m0 = blockIdx.y * BM, n0 = blockIdx.x * BN;
  int zz = blockIdx.z, ks = 0;
  const char* Ab;
  const char* Bb;
  if constexpr (EPI == 2) {
    zz = blockIdx.z >> 3;
    ks = blockIdx.z & 7;
    Ab = (const char*)(A + sA * zz + ks * 128);
    Bb = (const char*)(BT + sBT * zz + ks * 128);
  } else {
    Ab = (const char*)(A + sA * zz);
    Bb = (const char*)(BT + sBT * zz);
  }
  const long lda2 = (long)lda * 2, ldb2 = (long)ldb * 2;

  int rA0, qA0, rA1, qA1;
  invswz(t, rA0, qA0);
  invswz(t + 256, rA1, qA1);
  const int wofs = (t & 192) * 16;

  f32x4 acc[FM][FN] = {};

  auto stage = [&](char* Ad, char* Bd, int k0) {
    const long kb = (long)k0 * 2;
    GLL(Ab + (long)(m0 + rA0) * lda2 + kb + qA0, Ad + wofs);
    if constexpr (BM == 128) GLL(Ab + (long)(m0 + rA1) * lda2 + kb + qA1, Ad + 4096 + wofs);
    GLL(Bb + (long)(n0 + rA0) * ldb2 + kb + qA0, Bd + wofs);
    if constexpr (BN == 128) GLL(Bb + (long)(n0 + rA1) * ldb2 + kb + qA1, Bd + 4096 + wofs);
  };
  auto compute = [&](const char* A_, const char* B_) {
    bf16x8 af[FM], bfv[FN];
#pragma unroll
    for (int mi = 0; mi < FM; mi++) {
      int la = (wm + mi * 16 + llo) * 64 + lhi * 16;
      af[mi] = *(const bf16x8*)(A_ + fwdswz(la));
    }
#pragma unroll
    for (int ni = 0; ni < FN; ni++) {
      int la = (wn + ni * 16 + llo) * 64 + lhi * 16;
      bfv[ni] = *(const bf16x8*)(B_ + fwdswz(la));
    }
#pragma unroll
    for (int mi = 0; mi < FM; mi++)
#pragma unroll
      for (int ni = 0; ni < FN; ni++)
        acc[mi][ni] =
            __builtin_amdgcn_mfma_f32_16x16x32_bf16(af[mi], bfv[ni], acc[mi][ni], 0, 0, 0);
  };

  const int nt = K / 32;  // even for all call sites
  stage(As0, Bs0, 0);
  for (int i = 0; i < nt / 2 - 1; i++) {
    stage(As1, Bs1, (2 * i + 1) * 32);
    waitcnt_vm<S>();   // tile 2i loads done; tile 2i+1's S stay in flight
    barrier_raw();
    compute(As0, Bs0);
    barrier_raw();     // all waves done reading As0/Bs0
    stage(As0, Bs0, (2 * i + 2) * 32);
    waitcnt_vm<S>();
    barrier_raw();
    compute(As1, Bs1);
    barrier_raw();
  }
  stage(As1, Bs1, (nt - 1) * 32);
  waitcnt_vm<S>();
  barrier_raw();
  compute(As0, Bs0);
  waitcnt_vm<0>();     // drain last tile
  barrier_raw();
  compute(As1, Bs1);

#pragma unroll
  for (int mi = 0; mi < FM; mi++)
#pragma unroll
    for (int ni = 0; ni < FN; ni++)
#pragma unroll
      for (int r = 0; r < 4; r++) {
        int m = m0 + wm + mi * 16 + lhi * 4 + r;
        int n = n0 + wn + ni * 16 + llo;
        float vv = acc[mi][ni][r];
        if constexpr (EPI == 0) {
          ((float*)Cp)[sC * zz + (long)m * ldc + n] = vv;
        } else if constexpr (EPI == 1) {
          ((u16*)Cp)[sC * zz + (long)m * ldc + n] = f2bf(vv * Gm[(long)m * NV + n]);
        } else {
          ((float*)Cp)[(long)ks * (NV * 256) + (long)m * 256 + zz * 64 + n] = vv;
        }
      }
}

// ---------------------------------------------------------------------------
// f32 tiled matmul for step 1 only (Wh = h @ W). 64x64 tile, BK=16.
// ---------------------------------------------------------------------------
__global__ __launch_bounds__(256) void mm_f32(
    const float* __restrict__ Ap, const float* __restrict__ Bp,
    float* __restrict__ Cp) {
  __shared__ float As[16][68];
  __shared__ float Bs[16][68];
  const int t = threadIdx.x;
  const int tx = t & 15, ty = t >> 4;
  const int m0 = blockIdx.y * 64, n0 = blockIdx.x * 64;
  const int lr = t >> 2, lc4 = (t & 3) * 4;
  const int bk = t >> 4, bn = (t & 15) * 4;
  float acc[4][4] = {};
  for (int k0 = 0; k0 < 256; k0 += 16) {
    float4 a4 = *(const float4*)(Ap + (long)(m0 + lr) * 256 + k0 + lc4);
    As[lc4 + 0][lr] = a4.x;
    As[lc4 + 1][lr] = a4.y;
    As[lc4 + 2][lr] = a4.z;
    As[lc4 + 3][lr] = a4.w;
    float4 b4 = *(const float4*)(Bp + (long)(k0 + bk) * 256 + n0 + bn);
    Bs[bk][bn + 0] = b4.x;
    Bs[bk][bn + 1] = b4.y;
    Bs[bk][bn + 2] = b4.z;
    Bs[bk][bn + 3] = b4.w;
    __syncthreads();
#pragma unroll
    for (int kk = 0; kk < 16; kk++) {
      float a[4], b[4];
      *(float4*)a = *(const float4*)&As[kk][ty * 4];
      *(float4*)b = *(const float4*)&Bs[kk][tx * 4];
#pragma unroll
      for (int i = 0; i < 4; i++)
#pragma unroll
        for (int j = 0; j < 4; j++) acc[i][j] = fmaf(a[i], b[j], acc[i][j]);
    }
    __syncthreads();
  }
#pragma unroll
  for (int i = 0; i < 4; i++)
#pragma unroll
    for (int j = 0; j < 4; j++)
      Cp[(long)(m0 + ty * 4 + i) * 256 + n0 + tx * 4 + j] = acc[i][j];
}

// Build Mbf[v][e] (bf16 1/0) and Mtbf[e][v] via LDS-tiled transpose.
__global__ __launch_bounds__(256) void k_conv(const int* __restrict__ inc,
                                              u16* __restrict__ Mbf,
                                              u16* __restrict__ Mtbf) {
  __shared__ u16 tile[64][65];
  const int e0 = blockIdx.x * 64, v0 = blockIdx.y * 64;
  const int t = threadIdx.x;
#pragma unroll
  for (int p = 0; p < 4; p++) {
    int r = p * 16 + (t >> 4);
    int c4 = (t & 15) * 4;
    int4 q = *(const int4*)(inc + (long)(v0 + r) * NE + e0 + c4);
    ushort4 w;
    w.x = q.x > 0 ? 0x3F80 : 0;
    w.y = q.y > 0 ? 0x3F80 : 0;
    w.z = q.z > 0 ? 0x3F80 : 0;
    w.w = q.w > 0 ? 0x3F80 : 0;
    *(ushort4*)&Mbf[(long)(v0 + r) * NE + e0 + c4] = w;
    tile[c4 + 0][r] = w.x;
    tile[c4 + 1][r] = w.y;
    tile[c4 + 2][r] = w.z;
    tile[c4 + 3][r] = w.w;
  }
  __syncthreads();
#pragma unroll
  for (int p = 0; p < 4; p++) {
    int er = p * 16 + (t >> 4);
    int vc4 = (t & 15) * 4;
    ushort4 w;
    w.x = tile[er][vc4 + 0];
    w.y = tile[er][vc4 + 1];
    w.z = tile[er][vc4 + 2];
    w.w = tile[er][vc4 + 3];
    *(ushort4*)&Mtbf[(long)(e0 + er) * NV + v0 + vc4] = w;
  }
}

// Whht[c][u] = bf16(Wh[u][c]) — transpose to [256][1024] bf16
__global__ __launch_bounds__(256) void k_trw(const float* __restrict__ Wh,
                                             u16* __restrict__ Whht) {
  __shared__ u16 tile[64][65];
  const int c0 = blockIdx.x * 64, v0 = blockIdx.y * 64;
  const int t = threadIdx.x;
#pragma unroll
  for (int p = 0; p < 4; p++) {
    int r = p * 16 + (t >> 4);
    int c4 = (t & 15) * 4;
    float4 q = *(const float4*)(Wh + (long)(v0 + r) * 256 + c0 + c4);
    tile[c4 + 0][r] = f2bf(q.x);
    tile[c4 + 1][r] = f2bf(q.y);
    tile[c4 + 2][r] = f2bf(q.z);
    tile[c4 + 3][r] = f2bf(q.w);
  }
  __syncthreads();
#pragma unroll
  for (int p = 0; p < 4; p++) {
    int cr = p * 16 + (t >> 4);
    int vc4 = (t & 15) * 4;
    ushort4 w;
    w.x = tile[cr][vc4 + 0];
    w.y = tile[cr][vc4 + 1];
    w.z = tile[cr][vc4 + 2];
    w.w = tile[cr][vc4 + 3];
    *(ushort4*)&Whht[(long)(c0 + cr) * NV + v0 + vc4] = w;
  }
}

// qv[v,h] = Whh[v,h,:].a_v ; qe[v,h] = Whh[v,h,:].a_e
__global__ __launch_bounds__(256) void k_qse1(const float* __restrict__ Wh,
                                              const float* __restrict__ attn_w,
                                              float* __restrict__ qv, float* __restrict__ qe) {
  int v = blockIdx.x, t = threadIdx.x;
  int d = t & 63, h = t >> 6;
  float x = Wh[(long)v * 256 + t];
  float pv = x * attn_w[d];
  float pe = x * attn_w[64 + d];
  for (int s = 32; s; s >>= 1) {
    pv += __shfl_down(pv, s);
    pe += __shfl_down(pe, s);
  }
  if (d == 0) {
    qv[v * 4 + h] = pv;
    qe[v * 4 + h] = pe;
  }
}

// Partial cnt_e and se-sums over a 32-vertex slab.
__global__ __launch_bounds__(256) void k_cntse(const int* __restrict__ inc,
                                               const float* __restrict__ qe,
                                               float* __restrict__ part) {
  int e = blockIdx.x * 256 + threadIdx.x;
  int b = blockIdx.y;
  int v0 = b * 32;
  float c = 0, s0 = 0, s1 = 0, s2 = 0, s3 = 0;
  for (int v = v0; v < v0 + 32; v++) {
    if (inc[(long)v * NE + e] > 0) {
      c += 1.f;
      s0 += qe[v * 4 + 0];
      s1 += qe[v * 4 + 1];
      s2 += qe[v * 4 + 2];
      s3 += qe[v * 4 + 3];
    }
  }
  part[(0 * 32 + b) * NE + e] = c;
  part[(1 * 32 + b) * NE + e] = s0;
  part[(2 * 32 + b) * NE + e] = s1;
  part[(3 * 32 + b) * NE + e] = s2;
  part[(4 * 32 + b) * NE + e] = s3;
}

// Deterministic reduction of the 32 slabs. se holds RAW sums.
__global__ __launch_bounds__(256) void k_sered(const float* __restrict__ part,
                                               float* __restrict__ cnt, float* __restrict__ se) {
  int e = blockIdx.x * 256 + threadIdx.x;
  int j = blockIdx.y;
  float s = 0;
  for (int b = 0; b < 32; b++) s += part[(j * 32 + b) * NE + e];
  if (j == 0)
    cnt[e] = s;
  else
    se[e * 4 + (j - 1)] = s;
}

// Per (v,u): gate G via 2->32->1 MLP, and wce (bf16) = ce . (enc_w @ a_c)
__global__ __launch_bounds__(256) void k_G(const float* __restrict__ ce,
                                           const float* __restrict__ enc_w,
                                           const float* __restrict__ attn_w,
                                           const float* __restrict__ g1w,
                                           const float* __restrict__ g1b,
                                           const float* __restrict__ g2w,
                                           const float* __restrict__ g2b,
                                           float* __restrict__ G, u16* __restrict__ wce) {
  long idx = (long)blockIdx.x * 256 + threadIdx.x;
  float2 c = *(const float2*)(ce + idx * 2);
  float ew0 = 0, ew1 = 0;
#pragma unroll
  for (int j = 0; j < 8; j++) {
    float ac = attn_w[128 + j];
    ew0 += enc_w[j] * ac;
    ew1 += enc_w[8 + j] * ac;
  }
  wce[idx] = f2bf(c.x * ew0 + c.y * ew1);
  float s = g2b[0];
#pragma unroll
  for (int j = 0; j < 32; j++) {
    float zz = fmaxf(c.x * g1w[j] + c.y * g1w[32 + j] + g1b[j], 0.f);
    s = fmaf(zz, g2w[j], s);
  }
  G[idx] = 1.f / (1.f + expf(-s));
}

// Per v: scores -> leaky_relu -> mask -> softmax over E -> ap (bf16 planes), s_v
__global__ __launch_bounds__(256) void k_softmax(
    const float* __restrict__ P, const int* __restrict__ inc, const float* __restrict__ cnt,
    const float* __restrict__ qv, const float* __restrict__ se, const float* __restrict__ ce,
    const float* __restrict__ enc_w, const float* __restrict__ attn_w,
    const float* __restrict__ enc_b, u16* __restrict__ ap, float* __restrict__ sv) {
  int v = blockIdx.x, t = threadIdx.x;
  float ew0 = 0, ew1 = 0, ebac = 0;
#pragma unroll
  for (int j = 0; j < 8; j++) {
    float ac = attn_w[128 + j];
    ew0 += enc_w[j] * ac;
    ew1 += enc_w[8 + j] * ac;
    ebac += enc_b[j] * ac;
  }
  float dce = ce[((long)v * NV + v) * 2] * ew0 + ce[((long)v * NV + v) * 2 + 1] * ew1;
  float svh[4];
#pragma unroll
  for (int hh = 0; hh < 4; hh++) svh[hh] = qv[v * 4 + hh];

  float sc[8][4];
  float invn[8], msk[8];
  float mx[4] = {-3e38f, -3e38f, -3e38f, -3e38f};
  for (int i = 0; i < 8; i++) {
    int e = t + i * 256;
    float cnte = cnt[e];
    float mask = inc[(long)v * NE + e] > 0 ? 1.f : 0.f;
    float nve = cnte - mask;
    float inv = nve > 0.f ? 1.f / nve : 0.f;
    float rdg = 1.f / fmaxf(cnte, 1.f);
    invn[i] = inv;
    msk[i] = mask;
    float cc = inv * (P[(long)v * NE + e] - mask * dce) + ebac;
#pragma unroll
    for (int hh = 0; hh < 4; hh++) {
      float s = svh[hh] + se[e * 4 + hh] * rdg + cc;
      s = s > 0.f ? s : 0.2f * s;
      s = mask > 0.f ? s : -1e9f;
      sc[i][hh] = s;
      mx[hh] = fmaxf(mx[hh], s);
    }
  }
  __shared__ float red[4][256];
#pragma unroll
  for (int hh = 0; hh < 4; hh++) red[hh][t] = mx[hh];
  __syncthreads();
  for (int s = 128; s; s >>= 1) {
    if (t < s)
#pragma unroll
      for (int hh = 0; hh < 4; hh++) red[hh][t] = fmaxf(red[hh][t], red[hh][t + s]);
    __syncthreads();
  }
  float gm[4];
#pragma unroll
  for (int hh = 0; hh < 4; hh++) gm[hh] = red[hh][0];
  __syncthreads();

  float lsum[4] = {0, 0, 0, 0};
  for (int i = 0; i < 8; i++)
#pragma unroll
    for (int hh = 0; hh < 4; hh++) {
      float p = expf(sc[i][hh] - gm[hh]);
      sc[i][hh] = p;
      lsum[hh] += p;
    }
#pragma unroll
  for (int hh = 0; hh < 4; hh++) red[hh][t] = lsum[hh];
  __syncthreads();
  for (int s = 128; s; s >>= 1) {
    if (t < s)
#pragma unroll
      for (int hh = 0; hh < 4; hh++) red[hh][t] += red[hh][t + s];
    __syncthreads();
  }
  float inv_s[4];
#pragma unroll
  for (int hh = 0; hh < 4; hh++) inv_s[hh] = 1.f / red[hh][0];
  __syncthreads();

  float lsv[4] = {0, 0, 0, 0};
  for (int i = 0; i < 8; i++) {
    int e = t + i * 256;
#pragma unroll
    for (int hh = 0; hh < 4; hh++) {
      float a = sc[i][hh] * inv_s[hh] * msk[i] * invn[i];
      ap[(long)hh * NV * NE + (long)v * NE + e] = f2bf(a);
      lsv[hh] += a;
    }
  }
#pragma unroll
  for (int hh = 0; hh < 4; hh++) red[hh][t] = lsv[hh];
  __syncthreads();
  for (int s = 128; s; s >>= 1) {
    if (t < s)
#pragma unroll
      for (int hh = 0; hh < 4; hh++) red[hh][t] += red[hh][t + s];
    __syncthreads();
  }
  if (t == 0)
#pragma unroll
    for (int hh = 0; hh < 4; hh++) sv[v * 4 + hh] = red[hh][0];
}

// Fused: sum 8 split-K partials + residual + LayerNorm -> out
__global__ __launch_bounds__(256) void k_redln(
    const float* __restrict__ part, const float* __restrict__ Wh,
    const float* __restrict__ G, const float* __restrict__ sv,
    const float* __restrict__ lng, const float* __restrict__ lnb,
    float* __restrict__ out) {
  int v = blockIdx.x, t = threadIdx.x;
  float x = 0.f;
#pragma unroll
  for (int s = 0; s < 8; s++) x += part[(long)s * NV * 256 + (long)v * 256 + t];
  int z = t >> 6;
  float corr = 1.f - sv[v * 4 + z] * G[(long)v * NV + v];
  x += Wh[(long)v * 256 + t] * corr;
  __shared__ float red[256];
  red[t] = x;
  __syncthreads();
  for (int s = 128; s; s >>= 1) {
    if (t < s) red[t] += red[t + s];
    __syncthreads();
  }
  float mu = red[0] * (1.f / 256.f);
  __syncthreads();
  float d = x - mu;
  red[t] = d * d;
  __syncthreads();
  for (int s = 128; s; s >>= 1) {
    if (t < s) red[t] += red[t + s];
    __syncthreads();
  }
  float var = red[0] * (1.f / 256.f);
  out[(long)v * 256 + t] = d / sqrtf(var + 1e-5f) * lng[t] + lnb[t];
}

extern "C" void kernel_launch(void* const* d_in, const int* in_sizes, int n_in,
                              void* d_out, int out_size, void* d_ws, size_t ws_size,
                              hipStream_t stream) {
  const float* h = (const float*)d_in[0];
  const float* ce = (const float*)d_in[1];
  const float* W = (const float*)d_in[2];
  const float* attn_w = (const float*)d_in[3];
  const float* enc_w = (const float*)d_in[4];
  const float* enc_b = (const float*)d_in[5];
  const float* g1w = (const float*)d_in[6];
  const float* g1b = (const float*)d_in[7];
  const float* g2w = (const float*)d_in[8];
  const float* g2b = (const float*)d_in[9];
  const float* lng = (const float*)d_in[10];
  const float* lnb = (const float*)d_in[11];
  const int* inc = (const int*)d_in[12];
  float* out = (float*)d_out;

  size_t off = 0;
  char* base = (char*)d_ws;
  auto alloc = [&](size_t bytes) {
    void* p = base + off;
    off += (bytes + 255) & ~(size_t)255;
    return p;
  };
  float* Wh = (float*)alloc((size_t)NV * 256 * 4);
  float* cnt = (float*)alloc((size_t)NE * 4);
  float* qv = (float*)alloc((size_t)NV * 4 * 4);
  float* qe = (float*)alloc((size_t)NV * 4 * 4);
  float* se = (float*)alloc((size_t)NE * 4 * 4);
  float* sv = (float*)alloc((size_t)NV * 4 * 4);
  float* G = (float*)alloc((size_t)NV * NV * 4);
  u16* wce = (u16*)alloc((size_t)NV * NV * 2);
  u16* Mbf = (u16*)alloc((size_t)NV * NE * 2);
  u16* Whht = (u16*)alloc((size_t)256 * NV * 2);
  float* P = (float*)alloc((size_t)NV * NE * 4);  // also: split-K partials (8MB)
  u16* ap = (u16*)alloc((size_t)4 * NV * NE * 2);
  u16* Bh = (u16*)alloc((size_t)4 * NV * NV * 2);
  // aliases (lifetimes don't overlap):
  float* part = P;    // cnt/se partials (1.25MB), dead before P written
  u16* Mtbf = Bh;     // Mtbf (4MB) dead before Bh written
  float* part8 = P;   // step-8 split-K partials, P dead after k_softmax
  (void)ws_size;
  (void)in_sizes;
  (void)n_in;
  (void)out_size;

  // 0. bf16 incidence (row-major + transposed)
  k_conv<<<dim3(NE / 64, NV / 64), 256, 0, stream>>>(inc, Mbf, Mtbf);
  // 1. Wh = h @ W (f32)
  mm_f32<<<dim3(256 / 64, NV / 64), 256, 0, stream>>>(h, W, Wh);
  // 1b. Whht = Wh^T bf16
  k_trw<<<dim3(256 / 64, NV / 64), 256, 0, stream>>>(Wh, Whht);
  // 2. qv, qe
  k_qse1<<<NV, 256, 0, stream>>>(Wh, attn_w, qv, qe);
  // 3. cnt_e + se sums
  k_cntse<<<dim3(NE / 256, 32), 256, 0, stream>>>(inc, qe, part);
  k_sered<<<dim3(NE / 256, 5), 256, 0, stream>>>(part, cnt, se);
  // 4. G, wce(bf16)
  k_G<<<(NV * NV) / 256, 256, 0, stream>>>(ce, enc_w, attn_w, g1w, g1b, g2w, g2b, G, wce);
  // 5. P = wce @ M (M=1024, N=2048, K=1024), BT = Mtbf. 64x64 tiles -> 512 blocks.
  mfma_bt<64, 64, 0><<<dim3(NE / 64, NV / 64, 1), 256, 0, stream>>>(
      wce, NV, 0, Mtbf, NV, 0, P, NE, 0, NV, nullptr);
  // 6. softmax -> ap planes (bf16), s_v
  k_softmax<<<NV, 256, 0, stream>>>(P, inc, cnt, qv, se, ce, enc_w, attn_w, enc_b, ap, sv);
  // 7. Bh = (ap_h @ M^T) * G (4 x M=N=1024, K=2048). 128x64 tiles -> 512 blocks.
  mfma_bt<128, 64, 1><<<dim3(NV / 64, NV / 128, 4), 256, 0, stream>>>(
      ap, NE, (long)NV * NE, Mbf, NE, 0, Bh, NV, (long)NV * NV, NE, G);
  // 8. split-K=8 partials: part8[s][m][z*64+n] = Bh_z[m, ks] @ Whh_z[ks, n]
  mfma_bt<128, 64, 2><<<dim3(1, NV / 128, 32), 256, 0, stream>>>(
      Bh, NV, (long)NV * NV, Whht, NV, (long)64 * NV, part8, 256, 0, 128, nullptr);
  // 9. reduce partials + residual + LayerNorm
  k_redln<<<NV, 256, 0, stream>>>(part8, Wh, G, sv, lng, lnb, out);
}